// Round 11
// baseline (851.332 us; speedup 1.0000x reference)
//
#include <hip/hip_runtime.h>
#include <math.h>

// NeuroSAT RNN forward on MI355X — MFMA, weights LDS-staged, full bf16 shadow
// state, nontemporal stores for write-only f32 outputs (keep L2 for gathers).
namespace {
constexpr int NVARS    = 256;
constexpr int LITS_PER = 2 * NVARS;     // 512
constexpr int Bg       = 64;            // graphs
constexpr int NL       = Bg * LITS_PER; // 32768 literals
constexpr int CLS_PER  = 1024;
constexpr int NC       = Bg * CLS_PER;  // 65536 clauses
constexpr int NE       = NC * 3;        // 196608 edges (K=3)
constexpr int D        = 128;
constexpr int T        = 8;             // num_iters (fixed scalar input)

// d_out flat layout (reference tuple order)
constexpr size_t OFF_VOTE  = 0;                                  // [NL]
constexpr size_t OFF_XL    = (size_t)NL;                         // [NL*D]   (x_l state)
constexpr size_t OFF_POOL  = OFF_XL + (size_t)NL * D;            // [Bg]
constexpr size_t OFF_TLAST = OFF_POOL + Bg;                      // [NL]
constexpr size_t OFF_TALL  = OFF_TLAST + NL;                     // [(T+1)*NL]
constexpr size_t OFF_CALL  = OFF_TALL + (size_t)(T + 1) * NL;    // [(T+1)*NC*D] (x_c state)
constexpr size_t OFF_T0    = OFF_CALL + (size_t)(T + 1) * NC * D;// [NL]

// packed weights, single bf16 plane per matrix, frag order [n][ks][lane][8]:
// 0: W_ih_lc | 1: W_hh_lc | 2: W_hh_cl | 3: W_ih_cl[:, :128] | 4: W_ih_cl[:, 128:]
constexpr int PKM    = 16384;           // ushorts per matrix
constexpr int PK_TOT = 5 * PKM;         // 81920
constexpr size_t SHM_LC = 2 * PKM * sizeof(unsigned short);          // 64 KB
constexpr size_t SHM_CL = 2 * PKM * sizeof(unsigned short) + 1536;   // 64 KB + scratch
} // namespace

typedef __attribute__((ext_vector_type(8))) short short8v;
typedef __attribute__((ext_vector_type(4))) float f32x4;

__device__ __forceinline__ unsigned short f2bf(float v) {
    unsigned u = __float_as_uint(v);
    return (unsigned short)((u + 0x7fffu + ((u >> 16) & 1u)) >> 16);  // RNE
}
__device__ __forceinline__ float bf2f(unsigned short b) {
    return __uint_as_float(((unsigned)b) << 16);
}
__device__ __forceinline__ void cvt_frag(const float (&v)[8], short8v& ah, short8v& al) {
    #pragma unroll
    for (int j = 0; j < 8; j++) {
        unsigned short h = f2bf(v[j]);
        ah[j] = (short)h;
        al[j] = (short)f2bf(v[j] - bf2f(h));
    }
}
__device__ __forceinline__ float ftanh(float x) {
    float e = __builtin_amdgcn_exp2f(x * 2.885390081777926814f);
    return 1.0f - 2.0f * __builtin_amdgcn_rcpf(e + 1.0f);
}
// bf16x2: A split (ah+al), B single bf16 plane from LDS. 2 MFMAs, 1 LDS read.
__device__ __forceinline__ void mm2(f32x4& c, short8v ah, short8v al,
                                    const unsigned short* buf, int off) {
    short8v b = *(const short8v*)(buf + off);
    c = __builtin_amdgcn_mfma_f32_16x16x32_bf16(ah, b, c, 0, 0, 0);
    c = __builtin_amdgcn_mfma_f32_16x16x32_bf16(al, b, c, 0, 0, 0);
}
// pure-bf16 A (exact): 1 MFMA, B from LDS
__device__ __forceinline__ void mm1(f32x4& c, short8v a,
                                    const unsigned short* buf, int off) {
    short8v b = *(const short8v*)(buf + off);
    c = __builtin_amdgcn_mfma_f32_16x16x32_bf16(a, b, c, 0, 0, 0);
}
// pure-bf16 A, B from global (L2-hot 32 KB)
__device__ __forceinline__ void mm1g(f32x4& c, short8v a,
                                     const unsigned short* __restrict__ buf, int off) {
    short8v b = *(const short8v*)(buf + off);
    c = __builtin_amdgcn_mfma_f32_16x16x32_bf16(a, b, c, 0, 0, 0);
}
__device__ __forceinline__ void ntst(float* p, float v) { __builtin_nontemporal_store(v, p); }

// ---------------- W packing (single plane) -----------------------------------
__global__ __launch_bounds__(256) void pack5(
    const float* __restrict__ ihlc, const float* __restrict__ hhlc,
    const float* __restrict__ hhcl, const float* __restrict__ ihcl,
    unsigned short* __restrict__ pk) {
    int idx = blockIdx.x * 256 + threadIdx.x;
    int mat = idx >> 14, rel = idx & 16383;
    int j = rel & 7, lane = (rel >> 3) & 63, ks = (rel >> 9) & 3, n = rel >> 11;
    int r = n * 16 + (lane & 15);
    int k = ks * 32 + (lane >> 4) * 8 + j;
    float w;
    if (mat == 0)      w = ihlc[r * 128 + k];
    else if (mat == 1) w = hhlc[r * 128 + k];
    else if (mat == 2) w = hhcl[r * 128 + k];
    else if (mat == 3) w = ihcl[r * 256 + k];
    else               w = ihcl[r * 256 + 128 + k];
    pk[mat * PKM + rel] = f2bf(w);
}

// ---------------- CSR build --------------------------------------------------
__global__ void csr_count(const int* __restrict__ edge_lit, int* __restrict__ counts) {
    int e = blockIdx.x * blockDim.x + threadIdx.x;
    if (e < NE) atomicAdd(&counts[edge_lit[e]], 1);
}

__global__ __launch_bounds__(1024) void csr_scan(const int* __restrict__ counts,
                                                 int* __restrict__ offs,
                                                 int* __restrict__ cursor) {
    __shared__ int part[1024];
    const int t = threadIdx.x;
    const int base = t * 32;
    int local[32];
    int s = 0;
    for (int i = 0; i < 32; i++) { local[i] = s; s += counts[base + i]; }
    part[t] = s;
    __syncthreads();
    for (int d = 1; d < 1024; d <<= 1) {
        int v = 0;
        if (t >= d) v = part[t - d];
        __syncthreads();
        if (t >= d) part[t] += v;
        __syncthreads();
    }
    const int excl = (t == 0) ? 0 : part[t - 1];
    for (int i = 0; i < 32; i++) {
        int o = excl + local[i];
        offs[base + i] = o;
        cursor[base + i] = o;
    }
    if (t == 1023) offs[NL] = part[1023];
}

__global__ void csr_fill(const int* __restrict__ edge_lit, int* __restrict__ cursor,
                         int* __restrict__ csr) {
    int e = blockIdx.x * blockDim.x + threadIdx.x;
    if (e < NE) {
        int l = edge_lit[e];
        int p = atomicAdd(&cursor[l], 1);
        csr[p] = e / 3;
    }
}

__global__ void csr_sort(const int* __restrict__ offs, int* __restrict__ csr) {
    int l = blockIdx.x * blockDim.x + threadIdx.x;
    if (l >= NL) return;
    int s = offs[l], e = offs[l + 1];
    for (int i = s + 1; i < e; i++) {
        int v = csr[i];
        int j = i - 1;
        while (j >= s && csr[j] > v) { csr[j + 1] = csr[j]; j--; }
        csr[j + 1] = v;
    }
}

// per-64-literal-group degree sort (stable) -> perm of local indices
__global__ __launch_bounds__(64) void make_perm(const int* __restrict__ counts,
                                                int* __restrict__ perm) {
    __shared__ int d[64];
    const int b = blockIdx.x, i = threadIdx.x;
    d[i] = counts[b * 64 + i];
    __syncthreads();
    const int di = d[i];
    int rank = 0;
    for (int j = 0; j < 64; j++) {
        int dj = d[j];
        rank += (dj < di) || (dj == di && j < i);
    }
    perm[b * 64 + rank] = i;
}

// -------- init (both states in one launch): L2-normalize + shadows -----------
__global__ void init_norm(const float* __restrict__ x_l0, const float* __restrict__ x_c0,
                          float* __restrict__ xl_f32, unsigned short* __restrict__ xl_bf,
                          float* __restrict__ xc_f32, unsigned short* __restrict__ xc_bf,
                          float* __restrict__ norms,
                          const float* __restrict__ tv, float* __restrict__ tall,
                          float* __restrict__ t0) {
    int wave = (int)((blockIdx.x * blockDim.x + threadIdx.x) >> 6);
    int lane = threadIdx.x & 63;
    if (wave < NL) {
        const float* r = x_l0 + (size_t)wave * D;
        float v0 = r[lane], v1 = r[lane + 64];
        float ss = v0 * v0 + v1 * v1;
        #pragma unroll
        for (int m = 32; m; m >>= 1) ss += __shfl_xor(ss, m);
        float rn = 1.0f / sqrtf(ss);
        float y0 = v0 * rn, y1 = v1 * rn;
        ntst(xl_f32 + (size_t)wave * D + lane, y0);
        ntst(xl_f32 + (size_t)wave * D + lane + 64, y1);
        unsigned short* ob = xl_bf + (size_t)wave * D;
        ob[lane] = f2bf(y0);
        ob[lane + 64] = f2bf(y1);
        float dv = y0 * tv[lane] + y1 * tv[lane + 64];
        #pragma unroll
        for (int m = 32; m; m >>= 1) dv += __shfl_xor(dv, m);
        if (lane == 0) { ntst(tall + wave, dv); ntst(t0 + wave, dv); }
    } else if (wave < NL + NC) {
        const int row = wave - NL;
        const float* r = x_c0 + (size_t)row * D;
        float v0 = r[lane], v1 = r[lane + 64];
        float ss = v0 * v0 + v1 * v1;
        #pragma unroll
        for (int m = 32; m; m >>= 1) ss += __shfl_xor(ss, m);
        float rn = 1.0f / sqrtf(ss);
        ntst(xc_f32 + (size_t)row * D + lane, v0 * rn);
        ntst(xc_f32 + (size_t)row * D + lane + 64, v1 * rn);
        unsigned short* ob = xc_bf + (size_t)row * D;
        ob[lane] = f2bf(v0);                       // raw bf16 (pre-norm shadow)
        ob[lane + 64] = f2bf(v1);
        if (lane == 0) norms[row] = ss * rn;       // ||row||
    }
}

// -------- gather helper (CSR, bf16 source) -----------------------------------
__device__ __forceinline__ void gatherCSRb(const int* __restrict__ offs,
                                           const int* __restrict__ csr,
                                           const unsigned short* __restrict__ xcb,
                                           int arow, int g, float (&v)[4][8]) {
    #pragma unroll
    for (int ks = 0; ks < 4; ks++)
        #pragma unroll
        for (int j = 0; j < 8; j++) v[ks][j] = 0.f;
    const int s = offs[arow], e = offs[arow + 1];
    for (int p = s; p < e; p++) {
        const unsigned short* q = xcb + (size_t)csr[p] * D + g * 8;
        #pragma unroll
        for (int ks = 0; ks < 4; ks++) {
            short8v a = *(const short8v*)(q + ks * 32);
            #pragma unroll
            for (int j = 0; j < 8; j++) v[ks][j] += bf2f((unsigned short)a[j]);
        }
    }
}

// ---------------- LC: 512 blocks x 512 thr; 128 rows/block; wave=16 rows -----
// msg = 3 direct bf16 MFMA passes (exact); hidden = bf16*rcp(norm) via bf16x2.
__global__ __launch_bounds__(512, 4) void lc_mfma(
    const int* __restrict__ edge_lit, const unsigned short* __restrict__ xl_bf,
    unsigned short* xc_bf, float* norms,          // read t-1, write t (same rows)
    const unsigned short* __restrict__ pk,
    const float* __restrict__ bih, const float* __restrict__ bhh,
    float* __restrict__ xc_norm) {
    extern __shared__ __align__(16) unsigned short lds[];  // [0,PKM)=ih, [PKM,2PKM)=hh
    const int tid = threadIdx.x, wid = tid >> 6, lane = tid & 63;
    const int m = lane & 15, g = lane >> 4;
    const int p = blockIdx.x;
    const int blk = (p & 7) * 64 + (p >> 3);    // XCD-chunked, grid=512 bijective
    const int rowbase = blk * 128;
    const int arow = rowbase + wid * 16 + m;

    // stage ih_lc + hh_lc (64 KB contiguous in pk)
    {
        const short8v* src = (const short8v*)pk;
        short8v* dst = (short8v*)lds;
        #pragma unroll
        for (int i = 0; i < 8; i++) dst[i * 512 + tid] = src[i * 512 + tid];
    }
    const int e0 = edge_lit[3 * arow], e1 = edge_lit[3 * arow + 1], e2 = edge_lit[3 * arow + 2];
    const unsigned short* r0 = xl_bf + (size_t)e0 * D + g * 8;
    const unsigned short* r1 = xl_bf + (size_t)e1 * D + g * 8;
    const unsigned short* r2 = xl_bf + (size_t)e2 * D + g * 8;
    short8v aA[4], aB[4], aC[4];
    #pragma unroll
    for (int ks = 0; ks < 4; ks++) aA[ks] = *(const short8v*)(r0 + ks * 32);
    #pragma unroll
    for (int ks = 0; ks < 4; ks++) aB[ks] = *(const short8v*)(r1 + ks * 32);
    #pragma unroll
    for (int ks = 0; ks < 4; ks++) aC[ks] = *(const short8v*)(r2 + ks * 32);
    // hidden: bf16 pre-norm row; scale uniform per lane
    short8v hvb[4];
    {
        const unsigned short* hr = xc_bf + (size_t)arow * D + g * 8;
        #pragma unroll
        for (int ks = 0; ks < 4; ks++) hvb[ks] = *(const short8v*)(hr + ks * 32);
    }
    const float rnh = __builtin_amdgcn_rcpf(norms[arow]);
    __syncthreads();

    f32x4 acc[8];
    #pragma unroll
    for (int n = 0; n < 8; n++) acc[n] = (f32x4)0.f;

    // msg: 3 exact bf16 passes
    #pragma unroll
    for (int ks = 0; ks < 4; ks++)
        #pragma unroll
        for (int n = 0; n < 8; n++)
            mm1(acc[n], aA[ks], lds, ((n * 4 + ks) * 64 + lane) * 8);
    #pragma unroll
    for (int ks = 0; ks < 4; ks++)
        #pragma unroll
        for (int n = 0; n < 8; n++)
            mm1(acc[n], aB[ks], lds, ((n * 4 + ks) * 64 + lane) * 8);
    #pragma unroll
    for (int ks = 0; ks < 4; ks++)
        #pragma unroll
        for (int n = 0; n < 8; n++)
            mm1(acc[n], aC[ks], lds, ((n * 4 + ks) * 64 + lane) * 8);

    // hidden: scale + bf16x2
    {
        float vh[4][8];
        #pragma unroll
        for (int ks = 0; ks < 4; ks++)
            #pragma unroll
            for (int j = 0; j < 8; j++)
                vh[ks][j] = bf2f((unsigned short)hvb[ks][j]) * rnh;
        short8v ah[4], al[4];
        #pragma unroll
        for (int ks = 0; ks < 4; ks++) cvt_frag(vh[ks], ah[ks], al[ks]);
        #pragma unroll
        for (int ks = 0; ks < 4; ks++)
            #pragma unroll
            for (int n = 0; n < 8; n++)
                mm2(acc[n], ah[ks], al[ks], lds + PKM, ((n * 4 + ks) * 64 + lane) * 8);
    }

    float bias[8];
    #pragma unroll
    for (int n = 0; n < 8; n++) bias[n] = bih[n * 16 + m] + bhh[n * 16 + m];

    const int obase = rowbase + wid * 16 + g * 4;
    #pragma unroll
    for (int r = 0; r < 4; r++) {
        float w[8], ss = 0.f;
        #pragma unroll
        for (int n = 0; n < 8; n++) { w[n] = ftanh(acc[n][r] + bias[n]); ss += w[n] * w[n]; }
        ss += __shfl_xor(ss, 1); ss += __shfl_xor(ss, 2);
        ss += __shfl_xor(ss, 4); ss += __shfl_xor(ss, 8);
        const float rn = __builtin_amdgcn_rsqf(ss);
        const size_t rowoff = (size_t)(obase + r) * D + m;
        #pragma unroll
        for (int n = 0; n < 8; n++) {
            ntst(xc_norm + rowoff + n * 16, w[n] * rn); // f32 output: write-only -> nt
            xc_bf[rowoff + n * 16] = f2bf(w[n]);        // pre-norm bf16 (re-read) -> cached
        }
        if (m == 0) norms[obase + r] = ss * rn;         // ||row|| for next iter
    }
}

// ------- CL: 512 blocks x 512 thr; 64 rows/block; wave=16 rows x N-half ------
// flip-W read from global (L2-hot 32 KB): no restage, 2 barriers total.
__global__ __launch_bounds__(512, 4) void cl_mfma(
    const int* __restrict__ offs, const int* __restrict__ csr,
    const int* __restrict__ perm,
    const unsigned short* __restrict__ xc_bf,
    const unsigned short* __restrict__ xl_src,    // bf16 normalized state (read)
    const unsigned short* __restrict__ pk,
    const float* __restrict__ bih, const float* __restrict__ bhh,
    const float* __restrict__ tv, const float* __restrict__ vw,
    const float* __restrict__ vb,
    unsigned short* __restrict__ xl_dst,          // bf16 normalized state (write)
    float* __restrict__ xl_out,                   // f32 output (t==T only, else null)
    float* __restrict__ truth, float* __restrict__ truth2, float* __restrict__ vote) {
    extern __shared__ __align__(16) unsigned short lds[];
    // buf0 [0,PKM): ih_msg ; buf1 [PKM,2PKM): hh ; flip-W stays in global
    float* scr = (float*)(lds + 2 * PKM);
    float* ssx = scr; float* twx = scr + 128; float* vwx = scr + 256;

    const int tid = threadIdx.x, wid = tid >> 6, lane = tid & 63;
    const int m = lane & 15, g = lane >> 4;
    const int rw = wid >> 1, nh = wid & 1, nbase = nh * 4;
    const int p0 = blockIdx.x;
    const int blk = (p0 & 7) * 64 + (p0 >> 3);
    const int lbase = blk * 64;
    const int arow = lbase + perm[lbase + rw * 16 + m];

    // stage buf0=ih_msg (mat3), buf1=hh (mat2)
    {
        const short8v* srcA = (const short8v*)(pk + 3 * PKM);
        const short8v* srcB = (const short8v*)(pk + 2 * PKM);
        short8v* d0 = (short8v*)lds;
        short8v* d1 = (short8v*)(lds + PKM);
        #pragma unroll
        for (int i = 0; i < 4; i++) d0[i * 512 + tid] = srcA[i * 512 + tid];
        #pragma unroll
        for (int i = 0; i < 4; i++) d1[i * 512 + tid] = srcB[i * 512 + tid];
    }
    float v[4][8];
    gatherCSRb(offs, csr, xc_bf, arow, g, v);
    // hidden + flip bf16 frags (exact A; issue early)
    short8v hv[4], fv[4];
    {
        const unsigned short* hr = xl_src + (size_t)arow * D + g * 8;
        const unsigned short* fp = xl_src + (size_t)(arow ^ 256) * D + g * 8;
        #pragma unroll
        for (int ks = 0; ks < 4; ks++) { hv[ks] = *(const short8v*)(hr + ks * 32);
                                         fv[ks] = *(const short8v*)(fp + ks * 32); }
    }
    __syncthreads();                                   // b1

    short8v ah[4], al[4];
    #pragma unroll
    for (int ks = 0; ks < 4; ks++) cvt_frag(v[ks], ah[ks], al[ks]);

    f32x4 acc[4];
    #pragma unroll
    for (int n = 0; n < 4; n++) acc[n] = (f32x4)0.f;

    #pragma unroll
    for (int ks = 0; ks < 4; ks++)
        #pragma unroll
        for (int nn = 0; nn < 4; nn++)
            mm2(acc[nn], ah[ks], al[ks], lds, (((nbase + nn) * 4 + ks) * 64 + lane) * 8);

    #pragma unroll
    for (int ks = 0; ks < 4; ks++)
        #pragma unroll
        for (int nn = 0; nn < 4; nn++)
            mm1(acc[nn], hv[ks], lds + PKM, (((nbase + nn) * 4 + ks) * 64 + lane) * 8);

    const unsigned short* pkF = pk + 4 * PKM;          // ih_flip from global (L2)
    #pragma unroll
    for (int ks = 0; ks < 4; ks++)
        #pragma unroll
        for (int nn = 0; nn < 4; nn++)
            mm1g(acc[nn], fv[ks], pkF, (((nbase + nn) * 4 + ks) * 64 + lane) * 8);

    float bias[4], tvv[4], vwv[4];
    #pragma unroll
    for (int nn = 0; nn < 4; nn++) {
        int n = nbase + nn;
        bias[nn] = bih[n * 16 + m] + bhh[n * 16 + m];
        tvv[nn] = tv[n * 16 + m];
        vwv[nn] = vote ? vw[n * 16 + m] : 0.f;
    }
    float wv[4][4];
    #pragma unroll
    for (int r = 0; r < 4; r++) {
        float ssp = 0.f, twp = 0.f, vwp = 0.f;
        #pragma unroll
        for (int nn = 0; nn < 4; nn++) {
            float w = ftanh(acc[nn][r] + bias[nn]);
            wv[r][nn] = w;
            ssp += w * w; twp += w * tvv[nn]; vwp += w * vwv[nn];
        }
        ssp += __shfl_xor(ssp, 1); ssp += __shfl_xor(ssp, 2);
        ssp += __shfl_xor(ssp, 4); ssp += __shfl_xor(ssp, 8);
        twp += __shfl_xor(twp, 1); twp += __shfl_xor(twp, 2);
        twp += __shfl_xor(twp, 4); twp += __shfl_xor(twp, 8);
        if (vote) {
            vwp += __shfl_xor(vwp, 1); vwp += __shfl_xor(vwp, 2);
            vwp += __shfl_xor(vwp, 4); vwp += __shfl_xor(vwp, 8);
        }
        if (m == 0) {
            int rl = rw * 16 + g * 4 + r;
            ssx[rl * 2 + nh] = ssp;
            twx[rl * 2 + nh] = twp;
            if (vote) vwx[rl * 2 + nh] = vwp;
        }
    }
    __syncthreads();                                   // b2
    const float vb0 = vote ? vb[0] : 0.f;
    #pragma unroll
    for (int r = 0; r < 4; r++) {
        const int rl = rw * 16 + g * 4 + r;
        const int grow = lbase + perm[lbase + rl];
        const float ss = ssx[rl * 2] + ssx[rl * 2 + 1];
        const float rn = __builtin_amdgcn_rsqf(ss);
        const size_t rowoff = (size_t)grow * D + m;
        #pragma unroll
        for (int nn = 0; nn < 4; nn++) {
            const float y = wv[r][nn] * rn;
            xl_dst[rowoff + (nbase + nn) * 16] = f2bf(y);       // re-read -> cached
            if (xl_out) ntst(xl_out + rowoff + (nbase + nn) * 16, y);
        }
        if (m == 0 && nh == 0) {
            const float td = rn * (twx[rl * 2] + twx[rl * 2 + 1]);
            ntst(truth + grow, td);
            if (truth2) ntst(truth2 + grow, td);
            if (vote) ntst(vote + grow, rn * (vwx[rl * 2] + vwx[rl * 2 + 1]) + vb0);
        }
    }
}

// ---------------- mean-pool --------------------------------------------------
__global__ void pool_kernel(const float* __restrict__ votes, float* __restrict__ pool) {
    __shared__ float s[4];
    int g = blockIdx.x, t = threadIdx.x;
    float v = votes[g * LITS_PER + t] + votes[g * LITS_PER + 256 + t];
    #pragma unroll
    for (int m = 32; m; m >>= 1) v += __shfl_xor(v, m);
    if ((t & 63) == 0) s[t >> 6] = v;
    __syncthreads();
    if (t == 0) pool[g] = (s[0] + s[1] + s[2] + s[3]) * (1.0f / LITS_PER);
}

// ---------------- launch ----------------------------------------------------
extern "C" void kernel_launch(void* const* d_in, const int* in_sizes, int n_in,
                              void* d_out, int out_size, void* d_ws, size_t ws_size,
                              hipStream_t stream) {
    const int*   edge_lit = (const int*)d_in[1];
    const float* x_l0     = (const float*)d_in[2];
    const float* x_c0     = (const float*)d_in[3];
    const float* W_ih_lc  = (const float*)d_in[4];
    const float* W_hh_lc  = (const float*)d_in[5];
    const float* b_ih_lc  = (const float*)d_in[6];
    const float* b_hh_lc  = (const float*)d_in[7];
    const float* W_ih_cl  = (const float*)d_in[8];
    const float* W_hh_cl  = (const float*)d_in[9];
    const float* b_ih_cl  = (const float*)d_in[10];
    const float* b_hh_cl  = (const float*)d_in[11];
    const float* L_vote_w = (const float*)d_in[12];
    const float* L_vote_b = (const float*)d_in[13];
    const float* true_vec = (const float*)d_in[14];
    // d_in[15] = num_iters (=8, compile-time T)

    float* out   = (float*)d_out;
    float* xl_o  = out + OFF_XL;
    float* call  = out + OFF_CALL;
    float* tall  = out + OFF_TALL;

    // workspace (16B-aligned slices)
    unsigned short* xc_bf  = (unsigned short*)d_ws;          // NC*D bf16
    unsigned short* xl_bf0 = xc_bf + (size_t)NC * D;         // NL*D bf16
    unsigned short* xl_bf1 = xl_bf0 + (size_t)NL * D;        // NL*D bf16
    unsigned short* pk     = xl_bf1 + (size_t)NL * D;        // PK_TOT
    float* norms = (float*)(pk + PK_TOT);                    // NC
    int* counts = (int*)(norms + NC);                        // NL
    int* offs   = counts + NL;                               // NL+1
    int* cursor = offs + NL + 1;                             // NL
    int* csr    = cursor + NL;                               // NE
    int* perm   = csr + NE;                                  // NL

    hipMemsetAsync(counts, 0, NL * sizeof(int), stream);

    pack5<<<PK_TOT / 256, 256, 0, stream>>>(W_ih_lc, W_hh_lc, W_hh_cl, W_ih_cl, pk);
    csr_count<<<NE / 256, 256, 0, stream>>>(edge_lit, counts);
    csr_scan<<<1, 1024, 0, stream>>>(counts, offs, cursor);
    csr_fill<<<NE / 256, 256, 0, stream>>>(edge_lit, cursor, csr);
    csr_sort<<<NL / 256, 256, 0, stream>>>(offs, csr);
    make_perm<<<NL / 64, 64, 0, stream>>>(counts, perm);

    init_norm<<<(NL + NC) / 4, 256, 0, stream>>>(
        x_l0, x_c0, xl_o, xl_bf0, call, xc_bf, norms,
        true_vec, tall, out + OFF_T0);

    for (int t = 1; t <= T; t++) {
        const unsigned short* src = (t & 1) ? xl_bf0 : xl_bf1;
        unsigned short*       dst = (t & 1) ? xl_bf1 : xl_bf0;
        lc_mfma<<<NC / 128, 512, SHM_LC, stream>>>(
            edge_lit, src, xc_bf, norms, pk, b_ih_lc, b_hh_lc,
            call + (size_t)t * NC * D);
        cl_mfma<<<NL / 64, 512, SHM_CL, stream>>>(
            offs, csr, perm, xc_bf, src, pk,
            b_ih_cl, b_hh_cl, true_vec, L_vote_w, L_vote_b,
            dst, (t == T) ? xl_o : nullptr, tall + (size_t)t * NL,
            (t == T) ? out + OFF_TLAST : nullptr,
            (t == T) ? out + OFF_VOTE : nullptr);
    }

    pool_kernel<<<Bg, 256, 0, stream>>>(out + OFF_VOTE, out + OFF_POOL);
}

// Round 12
// 492.396 us; speedup vs baseline: 1.7290x; 1.7290x over previous
//
#include <hip/hip_runtime.h>
#include <math.h>

// NeuroSAT RNN forward on MI355X — round-10 structure + nontemporal stores for
// write-only f32 outputs (single-variable A/B vs round 10).
namespace {
constexpr int NVARS    = 256;
constexpr int LITS_PER = 2 * NVARS;     // 512
constexpr int Bg       = 64;            // graphs
constexpr int NL       = Bg * LITS_PER; // 32768 literals
constexpr int CLS_PER  = 1024;
constexpr int NC       = Bg * CLS_PER;  // 65536 clauses
constexpr int NE       = NC * 3;        // 196608 edges (K=3)
constexpr int D        = 128;
constexpr int T        = 8;             // num_iters (fixed scalar input)

// d_out flat layout (reference tuple order)
constexpr size_t OFF_VOTE  = 0;                                  // [NL]
constexpr size_t OFF_XL    = (size_t)NL;                         // [NL*D]   (x_l state)
constexpr size_t OFF_POOL  = OFF_XL + (size_t)NL * D;            // [Bg]
constexpr size_t OFF_TLAST = OFF_POOL + Bg;                      // [NL]
constexpr size_t OFF_TALL  = OFF_TLAST + NL;                     // [(T+1)*NL]
constexpr size_t OFF_CALL  = OFF_TALL + (size_t)(T + 1) * NL;    // [(T+1)*NC*D] (x_c state)
constexpr size_t OFF_T0    = OFF_CALL + (size_t)(T + 1) * NC * D;// [NL]

// packed weights, single bf16 plane per matrix, frag order [n][ks][lane][8]:
// 0: W_ih_lc | 1: W_hh_lc | 2: W_hh_cl | 3: W_ih_cl[:, :128] | 4: W_ih_cl[:, 128:]
constexpr int PKM    = 16384;           // ushorts per matrix
constexpr int PK_TOT = 5 * PKM;         // 81920
constexpr size_t SHM_LC = 2 * PKM * sizeof(unsigned short);          // 64 KB
constexpr size_t SHM_CL = 2 * PKM * sizeof(unsigned short) + 1536;   // 64 KB + scratch
} // namespace

typedef __attribute__((ext_vector_type(8))) short short8v;
typedef __attribute__((ext_vector_type(4))) float f32x4;

__device__ __forceinline__ unsigned short f2bf(float v) {
    unsigned u = __float_as_uint(v);
    return (unsigned short)((u + 0x7fffu + ((u >> 16) & 1u)) >> 16);  // RNE
}
__device__ __forceinline__ float bf2f(unsigned short b) {
    return __uint_as_float(((unsigned)b) << 16);
}
__device__ __forceinline__ void cvt_frag(const float (&v)[8], short8v& ah, short8v& al) {
    #pragma unroll
    for (int j = 0; j < 8; j++) {
        unsigned short h = f2bf(v[j]);
        ah[j] = (short)h;
        al[j] = (short)f2bf(v[j] - bf2f(h));
    }
}
__device__ __forceinline__ float ftanh(float x) {
    float e = __builtin_amdgcn_exp2f(x * 2.885390081777926814f);
    return 1.0f - 2.0f * __builtin_amdgcn_rcpf(e + 1.0f);
}
// bf16x2: A split (ah+al), B single bf16 plane from LDS. 2 MFMAs, 1 LDS read.
__device__ __forceinline__ void mm2(f32x4& c, short8v ah, short8v al,
                                    const unsigned short* buf, int off) {
    short8v b = *(const short8v*)(buf + off);
    c = __builtin_amdgcn_mfma_f32_16x16x32_bf16(ah, b, c, 0, 0, 0);
    c = __builtin_amdgcn_mfma_f32_16x16x32_bf16(al, b, c, 0, 0, 0);
}
// pure-bf16 A (exact): 1 MFMA
__device__ __forceinline__ void mm1(f32x4& c, short8v a,
                                    const unsigned short* buf, int off) {
    short8v b = *(const short8v*)(buf + off);
    c = __builtin_amdgcn_mfma_f32_16x16x32_bf16(a, b, c, 0, 0, 0);
}
// nontemporal store: evict-first hint for write-only output streams
__device__ __forceinline__ void ntst(float* p, float v) { __builtin_nontemporal_store(v, p); }

// ---------------- W packing (single plane) -----------------------------------
__global__ __launch_bounds__(256) void pack5(
    const float* __restrict__ ihlc, const float* __restrict__ hhlc,
    const float* __restrict__ hhcl, const float* __restrict__ ihcl,
    unsigned short* __restrict__ pk) {
    int idx = blockIdx.x * 256 + threadIdx.x;
    int mat = idx >> 14, rel = idx & 16383;
    int j = rel & 7, lane = (rel >> 3) & 63, ks = (rel >> 9) & 3, n = rel >> 11;
    int r = n * 16 + (lane & 15);
    int k = ks * 32 + (lane >> 4) * 8 + j;
    float w;
    if (mat == 0)      w = ihlc[r * 128 + k];
    else if (mat == 1) w = hhlc[r * 128 + k];
    else if (mat == 2) w = hhcl[r * 128 + k];
    else if (mat == 3) w = ihcl[r * 256 + k];
    else               w = ihcl[r * 256 + 128 + k];
    pk[mat * PKM + rel] = f2bf(w);
}

// ---------------- CSR build --------------------------------------------------
__global__ void csr_count(const int* __restrict__ edge_lit, int* __restrict__ counts) {
    int e = blockIdx.x * blockDim.x + threadIdx.x;
    if (e < NE) atomicAdd(&counts[edge_lit[e]], 1);
}

__global__ __launch_bounds__(1024) void csr_scan(const int* __restrict__ counts,
                                                 int* __restrict__ offs,
                                                 int* __restrict__ cursor) {
    __shared__ int part[1024];
    const int t = threadIdx.x;
    const int base = t * 32;
    int local[32];
    int s = 0;
    for (int i = 0; i < 32; i++) { local[i] = s; s += counts[base + i]; }
    part[t] = s;
    __syncthreads();
    for (int d = 1; d < 1024; d <<= 1) {
        int v = 0;
        if (t >= d) v = part[t - d];
        __syncthreads();
        if (t >= d) part[t] += v;
        __syncthreads();
    }
    const int excl = (t == 0) ? 0 : part[t - 1];
    for (int i = 0; i < 32; i++) {
        int o = excl + local[i];
        offs[base + i] = o;
        cursor[base + i] = o;
    }
    if (t == 1023) offs[NL] = part[1023];
}

__global__ void csr_fill(const int* __restrict__ edge_lit, int* __restrict__ cursor,
                         int* __restrict__ csr) {
    int e = blockIdx.x * blockDim.x + threadIdx.x;
    if (e < NE) {
        int l = edge_lit[e];
        int p = atomicAdd(&cursor[l], 1);
        csr[p] = e / 3;
    }
}

__global__ void csr_sort(const int* __restrict__ offs, int* __restrict__ csr) {
    int l = blockIdx.x * blockDim.x + threadIdx.x;
    if (l >= NL) return;
    int s = offs[l], e = offs[l + 1];
    for (int i = s + 1; i < e; i++) {
        int v = csr[i];
        int j = i - 1;
        while (j >= s && csr[j] > v) { csr[j + 1] = csr[j]; j--; }
        csr[j + 1] = v;
    }
}

// per-64-literal-group degree sort (stable) -> perm of local indices
__global__ __launch_bounds__(64) void make_perm(const int* __restrict__ counts,
                                                int* __restrict__ perm) {
    __shared__ int d[64];
    const int b = blockIdx.x, i = threadIdx.x;
    d[i] = counts[b * 64 + i];
    __syncthreads();
    const int di = d[i];
    int rank = 0;
    for (int j = 0; j < 64; j++) {
        int dj = d[j];
        rank += (dj < di) || (dj == di && j < i);
    }
    perm[b * 64 + rank] = i;
}

// -------- init: L2-normalize; bf shadow = normalized (norms==null) or raw+norms
__global__ void rownorm_dot(const float* __restrict__ in, float* __restrict__ out,
                            unsigned short* __restrict__ out_bf,
                            float* __restrict__ norms,
                            const float* __restrict__ dotw, float* __restrict__ dot0,
                            float* __restrict__ dot1, int nrows) {
    int wave = (int)((blockIdx.x * blockDim.x + threadIdx.x) >> 6);
    int lane = threadIdx.x & 63;
    if (wave >= nrows) return;
    const float* r = in + (size_t)wave * D;
    float v0 = r[lane], v1 = r[lane + 64];
    float ss = v0 * v0 + v1 * v1;
    #pragma unroll
    for (int m = 32; m; m >>= 1) ss += __shfl_xor(ss, m);
    float rn = 1.0f / sqrtf(ss);
    float y0 = v0 * rn, y1 = v1 * rn;
    ntst(out + (size_t)wave * D + lane, y0);        // f32 outputs: write-only
    ntst(out + (size_t)wave * D + lane + 64, y1);
    unsigned short* ob = out_bf + (size_t)wave * D;
    if (norms) {                       // store raw bf16 + row norm (x_c0 path)
        ob[lane] = f2bf(v0);
        ob[lane + 64] = f2bf(v1);
        if (lane == 0) norms[wave] = ss * rn;   // = sqrt(ss)
    } else {                           // store normalized bf16 (x_l0 path)
        ob[lane] = f2bf(y0);
        ob[lane + 64] = f2bf(y1);
    }
    if (dotw) {
        float dv = y0 * dotw[lane] + y1 * dotw[lane + 64];
        #pragma unroll
        for (int m = 32; m; m >>= 1) dv += __shfl_xor(dv, m);
        if (lane == 0) {
            ntst(dot0 + wave, dv);
            if (dot1) ntst(dot1 + wave, dv);
        }
    }
}

// -------- gather helpers (bf16 sources) --------------------------------------
__device__ __forceinline__ void gather3b(const int* __restrict__ ep,
                                         const unsigned short* __restrict__ xlb,
                                         int arow, int g, float (&v)[4][8]) {
    int e0 = ep[3 * arow], e1 = ep[3 * arow + 1], e2 = ep[3 * arow + 2];
    const unsigned short* r0 = xlb + (size_t)e0 * D + g * 8;
    const unsigned short* r1 = xlb + (size_t)e1 * D + g * 8;
    const unsigned short* r2 = xlb + (size_t)e2 * D + g * 8;
    #pragma unroll
    for (int ks = 0; ks < 4; ks++) {
        short8v a = *(const short8v*)(r0 + ks * 32);
        short8v b = *(const short8v*)(r1 + ks * 32);
        short8v c = *(const short8v*)(r2 + ks * 32);
        #pragma unroll
        for (int j = 0; j < 8; j++)
            v[ks][j] = bf2f((unsigned short)a[j]) + bf2f((unsigned short)b[j]) +
                       bf2f((unsigned short)c[j]);
    }
}

__device__ __forceinline__ void gatherCSRb(const int* __restrict__ offs,
                                           const int* __restrict__ csr,
                                           const unsigned short* __restrict__ xcb,
                                           int arow, int g, float (&v)[4][8]) {
    #pragma unroll
    for (int ks = 0; ks < 4; ks++)
        #pragma unroll
        for (int j = 0; j < 8; j++) v[ks][j] = 0.f;
    const int s = offs[arow], e = offs[arow + 1];
    for (int p = s; p < e; p++) {
        const unsigned short* q = xcb + (size_t)csr[p] * D + g * 8;
        #pragma unroll
        for (int ks = 0; ks < 4; ks++) {
            short8v a = *(const short8v*)(q + ks * 32);
            #pragma unroll
            for (int j = 0; j < 8; j++) v[ks][j] += bf2f((unsigned short)a[j]);
        }
    }
}

// ---------------- LC: 512 blocks x 512 thr; 128 rows/block; wave=16 rows -----
__global__ __launch_bounds__(512, 4) void lc_mfma(
    const int* __restrict__ edge_lit, const unsigned short* __restrict__ xl_bf,
    unsigned short* xc_bf, float* norms,          // read t-1, write t (same rows)
    const unsigned short* __restrict__ pk,
    const float* __restrict__ bih, const float* __restrict__ bhh,
    float* __restrict__ xc_norm) {
    extern __shared__ __align__(16) unsigned short lds[];  // [0,PKM)=ih, [PKM,2PKM)=hh
    const int tid = threadIdx.x, wid = tid >> 6, lane = tid & 63;
    const int m = lane & 15, g = lane >> 4;
    const int p = blockIdx.x;
    const int blk = (p & 7) * 64 + (p >> 3);    // XCD-chunked, grid=512 bijective
    const int rowbase = blk * 128;
    const int arow = rowbase + wid * 16 + m;

    // stage ih_lc + hh_lc (64 KB contiguous in pk)
    {
        const short8v* src = (const short8v*)pk;
        short8v* dst = (short8v*)lds;
        #pragma unroll
        for (int i = 0; i < 8; i++) dst[i * 512 + tid] = src[i * 512 + tid];
    }
    float v[4][8];
    gather3b(edge_lit, xl_bf, arow, g, v);
    // hidden: bf16 pre-norm row x (1/||row||); scale uniform per lane
    short8v hvb[4];
    {
        const unsigned short* hr = xc_bf + (size_t)arow * D + g * 8;
        #pragma unroll
        for (int ks = 0; ks < 4; ks++) hvb[ks] = *(const short8v*)(hr + ks * 32);
    }
    const float rnh = __builtin_amdgcn_rcpf(norms[arow]);
    __syncthreads();

    short8v ah[4], al[4];
    #pragma unroll
    for (int ks = 0; ks < 4; ks++) cvt_frag(v[ks], ah[ks], al[ks]);

    f32x4 acc[8];
    #pragma unroll
    for (int n = 0; n < 8; n++) acc[n] = (f32x4)0.f;

    #pragma unroll
    for (int ks = 0; ks < 4; ks++)
        #pragma unroll
        for (int n = 0; n < 8; n++)
            mm2(acc[n], ah[ks], al[ks], lds, ((n * 4 + ks) * 64 + lane) * 8);

    float vh[4][8];
    #pragma unroll
    for (int ks = 0; ks < 4; ks++)
        #pragma unroll
        for (int j = 0; j < 8; j++)
            vh[ks][j] = bf2f((unsigned short)hvb[ks][j]) * rnh;
    #pragma unroll
    for (int ks = 0; ks < 4; ks++) cvt_frag(vh[ks], ah[ks], al[ks]);
    #pragma unroll
    for (int ks = 0; ks < 4; ks++)
        #pragma unroll
        for (int n = 0; n < 8; n++)
            mm2(acc[n], ah[ks], al[ks], lds + PKM, ((n * 4 + ks) * 64 + lane) * 8);

    float bias[8];
    #pragma unroll
    for (int n = 0; n < 8; n++) bias[n] = bih[n * 16 + m] + bhh[n * 16 + m];

    const int obase = rowbase + wid * 16 + g * 4;
    #pragma unroll
    for (int r = 0; r < 4; r++) {
        float w[8], ss = 0.f;
        #pragma unroll
        for (int n = 0; n < 8; n++) { w[n] = ftanh(acc[n][r] + bias[n]); ss += w[n] * w[n]; }
        ss += __shfl_xor(ss, 1); ss += __shfl_xor(ss, 2);
        ss += __shfl_xor(ss, 4); ss += __shfl_xor(ss, 8);
        const float rn = __builtin_amdgcn_rsqf(ss);
        const size_t rowoff = (size_t)(obase + r) * D + m;
        #pragma unroll
        for (int n = 0; n < 8; n++) {
            ntst(xc_norm + rowoff + n * 16, w[n] * rn); // write-only f32 -> nt
            xc_bf[rowoff + n * 16] = f2bf(w[n]);        // re-read bf16 -> cached
        }
        if (m == 0) norms[obase + r] = ss * rn;         // ||row|| for next iter
    }
}

// ------- CL: 512 blocks x 512 thr; 64 rows/block; wave=16 rows x N-half ------
__global__ __launch_bounds__(512, 4) void cl_mfma(
    const int* __restrict__ offs, const int* __restrict__ csr,
    const int* __restrict__ perm,
    const unsigned short* __restrict__ xc_bf,
    const unsigned short* __restrict__ xl_src,    // bf16 normalized state (read)
    const unsigned short* __restrict__ pk,
    const float* __restrict__ bih, const float* __restrict__ bhh,
    const float* __restrict__ tv, const float* __restrict__ vw,
    const float* __restrict__ vb,
    unsigned short* __restrict__ xl_dst,          // bf16 normalized state (write)
    float* __restrict__ xl_out,                   // f32 output (t==T only, else null)
    float* __restrict__ truth, float* __restrict__ truth2, float* __restrict__ vote) {
    extern __shared__ __align__(16) unsigned short lds[];
    // buf0 [0,PKM): ih_msg -> later ih_flip ; buf1 [PKM,2PKM): hh
    float* scr = (float*)(lds + 2 * PKM);
    float* ssx = scr; float* twx = scr + 128; float* vwx = scr + 256;

    const int tid = threadIdx.x, wid = tid >> 6, lane = tid & 63;
    const int m = lane & 15, g = lane >> 4;
    const int rw = wid >> 1, nh = wid & 1, nbase = nh * 4;
    const int p0 = blockIdx.x;
    const int blk = (p0 & 7) * 64 + (p0 >> 3);
    const int lbase = blk * 64;
    const int arow = lbase + perm[lbase + rw * 16 + m];

    // stage buf0=ih_msg (mat3), buf1=hh (mat2)
    {
        const short8v* srcA = (const short8v*)(pk + 3 * PKM);
        const short8v* srcB = (const short8v*)(pk + 2 * PKM);
        short8v* d0 = (short8v*)lds;
        short8v* d1 = (short8v*)(lds + PKM);
        #pragma unroll
        for (int i = 0; i < 4; i++) d0[i * 512 + tid] = srcA[i * 512 + tid];
        #pragma unroll
        for (int i = 0; i < 4; i++) d1[i * 512 + tid] = srcB[i * 512 + tid];
    }
    float v[4][8];
    gatherCSRb(offs, csr, xc_bf, arow, g, v);
    // hidden + flip bf16 frags (exact A; issue early, land under msg MFMAs)
    short8v hv[4], fv[4];
    {
        const unsigned short* hr = xl_src + (size_t)arow * D + g * 8;
        const unsigned short* fp = xl_src + (size_t)(arow ^ 256) * D + g * 8;
        #pragma unroll
        for (int ks = 0; ks < 4; ks++) { hv[ks] = *(const short8v*)(hr + ks * 32);
                                         fv[ks] = *(const short8v*)(fp + ks * 32); }
    }
    __syncthreads();                                   // b1

    short8v ah[4], al[4];
    #pragma unroll
    for (int ks = 0; ks < 4; ks++) cvt_frag(v[ks], ah[ks], al[ks]);

    f32x4 acc[4];
    #pragma unroll
    for (int n = 0; n < 4; n++) acc[n] = (f32x4)0.f;

    // T14: prefetch flip-W to regs before msg MFMAs
    short8v fr[4];
    {
        const short8v* srcF = (const short8v*)(pk + 4 * PKM);  // ih_flip
        #pragma unroll
        for (int i = 0; i < 4; i++) fr[i] = srcF[i * 512 + tid];
    }

    #pragma unroll
    for (int ks = 0; ks < 4; ks++)
        #pragma unroll
        for (int nn = 0; nn < 4; nn++)
            mm2(acc[nn], ah[ks], al[ks], lds, (((nbase + nn) * 4 + ks) * 64 + lane) * 8);

    __syncthreads();                                   // b2: msg reads of buf0 done
    {
        short8v* d0 = (short8v*)lds;
        #pragma unroll
        for (int i = 0; i < 4; i++) d0[i * 512 + tid] = fr[i];
    }
    #pragma unroll
    for (int ks = 0; ks < 4; ks++)
        #pragma unroll
        for (int nn = 0; nn < 4; nn++)
            mm1(acc[nn], hv[ks], lds + PKM, (((nbase + nn) * 4 + ks) * 64 + lane) * 8);

    __syncthreads();                                   // b3: flip staged & visible
    #pragma unroll
    for (int ks = 0; ks < 4; ks++)
        #pragma unroll
        for (int nn = 0; nn < 4; nn++)
            mm1(acc[nn], fv[ks], lds, (((nbase + nn) * 4 + ks) * 64 + lane) * 8);

    float bias[4], tvv[4], vwv[4];
    #pragma unroll
    for (int nn = 0; nn < 4; nn++) {
        int n = nbase + nn;
        bias[nn] = bih[n * 16 + m] + bhh[n * 16 + m];
        tvv[nn] = tv[n * 16 + m];
        vwv[nn] = vote ? vw[n * 16 + m] : 0.f;
    }
    float wv[4][4];
    #pragma unroll
    for (int r = 0; r < 4; r++) {
        float ssp = 0.f, twp = 0.f, vwp = 0.f;
        #pragma unroll
        for (int nn = 0; nn < 4; nn++) {
            float w = ftanh(acc[nn][r] + bias[nn]);
            wv[r][nn] = w;
            ssp += w * w; twp += w * tvv[nn]; vwp += w * vwv[nn];
        }
        ssp += __shfl_xor(ssp, 1); ssp += __shfl_xor(ssp, 2);
        ssp += __shfl_xor(ssp, 4); ssp += __shfl_xor(ssp, 8);
        twp += __shfl_xor(twp, 1); twp += __shfl_xor(twp, 2);
        twp += __shfl_xor(twp, 4); twp += __shfl_xor(twp, 8);
        if (vote) {
            vwp += __shfl_xor(vwp, 1); vwp += __shfl_xor(vwp, 2);
            vwp += __shfl_xor(vwp, 4); vwp += __shfl_xor(vwp, 8);
        }
        if (m == 0) {
            int rl = rw * 16 + g * 4 + r;
            ssx[rl * 2 + nh] = ssp;
            twx[rl * 2 + nh] = twp;
            if (vote) vwx[rl * 2 + nh] = vwp;
        }
    }
    __syncthreads();                                   // b4
    const float vb0 = vote ? vb[0] : 0.f;
    #pragma unroll
    for (int r = 0; r < 4; r++) {
        const int rl = rw * 16 + g * 4 + r;
        const int grow = lbase + perm[lbase + rl];
        const float ss = ssx[rl * 2] + ssx[rl * 2 + 1];
        const float rn = __builtin_amdgcn_rsqf(ss);
        const size_t rowoff = (size_t)grow * D + m;
        #pragma unroll
        for (int nn = 0; nn < 4; nn++) {
            const float y = wv[r][nn] * rn;
            xl_dst[rowoff + (nbase + nn) * 16] = f2bf(y);           // re-read -> cached
            if (xl_out) ntst(xl_out + rowoff + (nbase + nn) * 16, y); // write-only -> nt
        }
        if (m == 0 && nh == 0) {
            const float td = rn * (twx[rl * 2] + twx[rl * 2 + 1]);
            ntst(truth + grow, td);
            if (truth2) ntst(truth2 + grow, td);
            if (vote) ntst(vote + grow, rn * (vwx[rl * 2] + vwx[rl * 2 + 1]) + vb0);
        }
    }
}

// ---------------- mean-pool --------------------------------------------------
__global__ void pool_kernel(const float* __restrict__ votes, float* __restrict__ pool) {
    __shared__ float s[4];
    int g = blockIdx.x, t = threadIdx.x;
    float v = votes[g * LITS_PER + t] + votes[g * LITS_PER + 256 + t];
    #pragma unroll
    for (int m = 32; m; m >>= 1) v += __shfl_xor(v, m);
    if ((t & 63) == 0) s[t >> 6] = v;
    __syncthreads();
    if (t == 0) pool[g] = (s[0] + s[1] + s[2] + s[3]) * (1.0f / LITS_PER);
}

// ---------------- launch ----------------------------------------------------
extern "C" void kernel_launch(void* const* d_in, const int* in_sizes, int n_in,
                              void* d_out, int out_size, void* d_ws, size_t ws_size,
                              hipStream_t stream) {
    const int*   edge_lit = (const int*)d_in[1];
    const float* x_l0     = (const float*)d_in[2];
    const float* x_c0     = (const float*)d_in[3];
    const float* W_ih_lc  = (const float*)d_in[4];
    const float* W_hh_lc  = (const float*)d_in[5];
    const float* b_ih_lc  = (const float*)d_in[6];
    const float* b_hh_lc  = (const float*)d_in[7];
    const float* W_ih_cl  = (const float*)d_in[8];
    const float* W_hh_cl  = (const float*)d_in[9];
    const float* b_ih_cl  = (const float*)d_in[10];
    const float* b_hh_cl  = (const float*)d_in[11];
    const float* L_vote_w = (const float*)d_in[12];
    const float* L_vote_b = (const float*)d_in[13];
    const float* true_vec = (const float*)d_in[14];
    // d_in[15] = num_iters (=8, compile-time T)

    float* out   = (float*)d_out;
    float* xl_o  = out + OFF_XL;
    float* call  = out + OFF_CALL;
    float* tall  = out + OFF_TALL;

    // workspace (16B-aligned slices)
    unsigned short* xc_bf  = (unsigned short*)d_ws;          // NC*D bf16
    unsigned short* xl_bf0 = xc_bf + (size_t)NC * D;         // NL*D bf16
    unsigned short* xl_bf1 = xl_bf0 + (size_t)NL * D;        // NL*D bf16
    unsigned short* pk     = xl_bf1 + (size_t)NL * D;        // PK_TOT
    float* norms = (float*)(pk + PK_TOT);                    // NC
    int* counts = (int*)(norms + NC);                        // NL
    int* offs   = counts + NL;                               // NL+1
    int* cursor = offs + NL + 1;                             // NL
    int* csr    = cursor + NL;                               // NE
    int* perm   = csr + NE;                                  // NL

    hipMemsetAsync(counts, 0, NL * sizeof(int), stream);

    pack5<<<PK_TOT / 256, 256, 0, stream>>>(W_ih_lc, W_hh_lc, W_hh_cl, W_ih_cl, pk);
    csr_count<<<NE / 256, 256, 0, stream>>>(edge_lit, counts);
    csr_scan<<<1, 1024, 0, stream>>>(counts, offs, cursor);
    csr_fill<<<NE / 256, 256, 0, stream>>>(edge_lit, cursor, csr);
    csr_sort<<<NL / 256, 256, 0, stream>>>(offs, csr);
    make_perm<<<NL / 64, 64, 0, stream>>>(counts, perm);

    // init: x_l -> normalized f32 (slot) + bf16 (xl_bf0) + truth0;
    //       x_c -> normalized f32 (call slice 0) + raw bf16 + norms
    rownorm_dot<<<NL / 4, 256, 0, stream>>>(x_l0, xl_o, xl_bf0, nullptr, true_vec,
                                            tall, out + OFF_T0, NL);
    rownorm_dot<<<NC / 4, 256, 0, stream>>>(x_c0, call, xc_bf, norms, nullptr,
                                            nullptr, nullptr, NC);

    for (int t = 1; t <= T; t++) {
        const unsigned short* src = (t & 1) ? xl_bf0 : xl_bf1;
        unsigned short*       dst = (t & 1) ? xl_bf1 : xl_bf0;
        lc_mfma<<<NC / 128, 512, SHM_LC, stream>>>(
            edge_lit, src, xc_bf, norms, pk, b_ih_lc, b_hh_lc,
            call + (size_t)t * NC * D);
        cl_mfma<<<NL / 64, 512, SHM_CL, stream>>>(
            offs, csr, perm, xc_bf, src, pk,
            b_ih_cl, b_hh_cl, true_vec, L_vote_w, L_vote_b,
            dst, (t == T) ? xl_o : nullptr, tall + (size_t)t * NL,
            (t == T) ? out + OFF_TLAST : nullptr,
            (t == T) ? out + OFF_VOTE : nullptr);
    }

    pool_kernel<<<Bg, 256, 0, stream>>>(out + OFF_VOTE, out + OFF_POOL);
}

// Round 13
// 474.821 us; speedup vs baseline: 1.7930x; 1.0370x over previous
//
#include <hip/hip_runtime.h>
#include <math.h>

// NeuroSAT RNN forward on MI355X — round-12 hot kernels + parallel group-CSR
// setup (no serial scan) + merged init. Hot-path numerics bit-identical to R12.
namespace {
constexpr int NVARS    = 256;
constexpr int LITS_PER = 2 * NVARS;     // 512
constexpr int Bg       = 64;            // graphs
constexpr int NL       = Bg * LITS_PER; // 32768 literals
constexpr int CLS_PER  = 1024;
constexpr int NC       = Bg * CLS_PER;  // 65536 clauses
constexpr int NE       = NC * 3;        // 196608 edges (K=3)
constexpr int D        = 128;
constexpr int T        = 8;             // num_iters (fixed scalar input)
constexpr int GCAP     = 1024;          // csr capacity per 64-literal group (mean 384)

// d_out flat layout (reference tuple order)
constexpr size_t OFF_VOTE  = 0;                                  // [NL]
constexpr size_t OFF_XL    = (size_t)NL;                         // [NL*D]   (x_l state)
constexpr size_t OFF_POOL  = OFF_XL + (size_t)NL * D;            // [Bg]
constexpr size_t OFF_TLAST = OFF_POOL + Bg;                      // [NL]
constexpr size_t OFF_TALL  = OFF_TLAST + NL;                     // [(T+1)*NL]
constexpr size_t OFF_CALL  = OFF_TALL + (size_t)(T + 1) * NL;    // [(T+1)*NC*D] (x_c state)
constexpr size_t OFF_T0    = OFF_CALL + (size_t)(T + 1) * NC * D;// [NL]

// packed weights, single bf16 plane per matrix, frag order [n][ks][lane][8]:
// 0: W_ih_lc | 1: W_hh_lc | 2: W_hh_cl | 3: W_ih_cl[:, :128] | 4: W_ih_cl[:, 128:]
constexpr int PKM    = 16384;           // ushorts per matrix
constexpr int PK_TOT = 5 * PKM;         // 81920
constexpr size_t SHM_LC = 2 * PKM * sizeof(unsigned short);          // 64 KB
constexpr size_t SHM_CL = 2 * PKM * sizeof(unsigned short) + 1536;   // 64 KB + scratch
} // namespace

typedef __attribute__((ext_vector_type(8))) short short8v;
typedef __attribute__((ext_vector_type(4))) float f32x4;

__device__ __forceinline__ unsigned short f2bf(float v) {
    unsigned u = __float_as_uint(v);
    return (unsigned short)((u + 0x7fffu + ((u >> 16) & 1u)) >> 16);  // RNE
}
__device__ __forceinline__ float bf2f(unsigned short b) {
    return __uint_as_float(((unsigned)b) << 16);
}
__device__ __forceinline__ void cvt_frag(const float (&v)[8], short8v& ah, short8v& al) {
    #pragma unroll
    for (int j = 0; j < 8; j++) {
        unsigned short h = f2bf(v[j]);
        ah[j] = (short)h;
        al[j] = (short)f2bf(v[j] - bf2f(h));
    }
}
__device__ __forceinline__ float ftanh(float x) {
    float e = __builtin_amdgcn_exp2f(x * 2.885390081777926814f);
    return 1.0f - 2.0f * __builtin_amdgcn_rcpf(e + 1.0f);
}
// bf16x2: A split (ah+al), B single bf16 plane from LDS. 2 MFMAs, 1 LDS read.
__device__ __forceinline__ void mm2(f32x4& c, short8v ah, short8v al,
                                    const unsigned short* buf, int off) {
    short8v b = *(const short8v*)(buf + off);
    c = __builtin_amdgcn_mfma_f32_16x16x32_bf16(ah, b, c, 0, 0, 0);
    c = __builtin_amdgcn_mfma_f32_16x16x32_bf16(al, b, c, 0, 0, 0);
}
// pure-bf16 A (exact): 1 MFMA
__device__ __forceinline__ void mm1(f32x4& c, short8v a,
                                    const unsigned short* buf, int off) {
    short8v b = *(const short8v*)(buf + off);
    c = __builtin_amdgcn_mfma_f32_16x16x32_bf16(a, b, c, 0, 0, 0);
}
// nontemporal store: evict-first hint for write-only output streams
__device__ __forceinline__ void ntst(float* p, float v) { __builtin_nontemporal_store(v, p); }

// ---------------- W packing (single plane) -----------------------------------
__global__ __launch_bounds__(256) void pack5(
    const float* __restrict__ ihlc, const float* __restrict__ hhlc,
    const float* __restrict__ hhcl, const float* __restrict__ ihcl,
    unsigned short* __restrict__ pk) {
    int idx = blockIdx.x * 256 + threadIdx.x;
    int mat = idx >> 14, rel = idx & 16383;
    int j = rel & 7, lane = (rel >> 3) & 63, ks = (rel >> 9) & 3, n = rel >> 11;
    int r = n * 16 + (lane & 15);
    int k = ks * 32 + (lane >> 4) * 8 + j;
    float w;
    if (mat == 0)      w = ihlc[r * 128 + k];
    else if (mat == 1) w = hhlc[r * 128 + k];
    else if (mat == 2) w = hhcl[r * 128 + k];
    else if (mat == 3) w = ihcl[r * 256 + k];
    else               w = ihcl[r * 256 + 128 + k];
    pk[mat * PKM + rel] = f2bf(w);
}

// ---------------- CSR build (group-strided, fully parallel) -------------------
__global__ void csr_count(const int* __restrict__ edge_lit, int* __restrict__ counts) {
    int e = blockIdx.x * blockDim.x + threadIdx.x;
    if (e < NE) atomicAdd(&counts[edge_lit[e]], 1);
}

// one 64-lane wave per 64-literal group: exclusive scan (offs/cursor) + degree-sort perm
__global__ __launch_bounds__(64) void group_scan(const int* __restrict__ counts,
                                                 int* __restrict__ offs,
                                                 int* __restrict__ cursor,
                                                 int* __restrict__ perm) {
    const int grp = blockIdx.x, i = threadIdx.x;
    const int l = grp * 64 + i;
    const int cnt = counts[l];
    // inclusive shfl scan -> exclusive
    int v = cnt;
    #pragma unroll
    for (int d = 1; d < 64; d <<= 1) {
        int up = __shfl_up(v, d);
        if (i >= d) v += up;
    }
    const int o = grp * GCAP + (v - cnt);
    offs[l] = o;
    cursor[l] = o;
    // stable degree ranking (ties by index) -> perm of local indices
    int rank = 0;
    #pragma unroll 8
    for (int j = 0; j < 64; j++) {
        int dj = __shfl(cnt, j);
        rank += (dj < cnt) || (dj == cnt && j < i);
    }
    perm[grp * 64 + rank] = i;
}

__global__ void csr_fill(const int* __restrict__ edge_lit, int* __restrict__ cursor,
                         int* __restrict__ csr) {
    int e = blockIdx.x * blockDim.x + threadIdx.x;
    if (e < NE) {
        int l = edge_lit[e];
        int p = atomicAdd(&cursor[l], 1);
        csr[p] = e / 3;
    }
}

__global__ void csr_sort(const int* __restrict__ offs, const int* __restrict__ counts,
                         int* __restrict__ csr) {
    int l = blockIdx.x * blockDim.x + threadIdx.x;
    if (l >= NL) return;
    int s = offs[l], e = s + counts[l];
    for (int i = s + 1; i < e; i++) {
        int v = csr[i];
        int j = i - 1;
        while (j >= s && csr[j] > v) { csr[j + 1] = csr[j]; j--; }
        csr[j + 1] = v;
    }
}

// -------- init (both states, one launch): L2-normalize + bf16 shadows --------
__global__ void init_norm(const float* __restrict__ x_l0, const float* __restrict__ x_c0,
                          float* __restrict__ xl_f32, unsigned short* __restrict__ xl_bf,
                          float* __restrict__ xc_f32, unsigned short* __restrict__ xc_bf,
                          float* __restrict__ norms,
                          const float* __restrict__ tv, float* __restrict__ tall,
                          float* __restrict__ t0) {
    int wave = (int)((blockIdx.x * blockDim.x + threadIdx.x) >> 6);
    int lane = threadIdx.x & 63;
    if (wave < NL) {
        const float* r = x_l0 + (size_t)wave * D;
        float v0 = r[lane], v1 = r[lane + 64];
        float ss = v0 * v0 + v1 * v1;
        #pragma unroll
        for (int m = 32; m; m >>= 1) ss += __shfl_xor(ss, m);
        float rn = 1.0f / sqrtf(ss);
        float y0 = v0 * rn, y1 = v1 * rn;
        ntst(xl_f32 + (size_t)wave * D + lane, y0);
        ntst(xl_f32 + (size_t)wave * D + lane + 64, y1);
        unsigned short* ob = xl_bf + (size_t)wave * D;
        ob[lane] = f2bf(y0);
        ob[lane + 64] = f2bf(y1);
        float dv = y0 * tv[lane] + y1 * tv[lane + 64];
        #pragma unroll
        for (int m = 32; m; m >>= 1) dv += __shfl_xor(dv, m);
        if (lane == 0) { ntst(tall + wave, dv); ntst(t0 + wave, dv); }
    } else if (wave < NL + NC) {
        const int row = wave - NL;
        const float* r = x_c0 + (size_t)row * D;
        float v0 = r[lane], v1 = r[lane + 64];
        float ss = v0 * v0 + v1 * v1;
        #pragma unroll
        for (int m = 32; m; m >>= 1) ss += __shfl_xor(ss, m);
        float rn = 1.0f / sqrtf(ss);
        ntst(xc_f32 + (size_t)row * D + lane, v0 * rn);
        ntst(xc_f32 + (size_t)row * D + lane + 64, v1 * rn);
        unsigned short* ob = xc_bf + (size_t)row * D;
        ob[lane] = f2bf(v0);                       // raw bf16 (pre-norm shadow)
        ob[lane + 64] = f2bf(v1);
        if (lane == 0) norms[row] = ss * rn;       // ||row||
    }
}

// -------- gather helpers (bf16 sources) --------------------------------------
__device__ __forceinline__ void gather3b(const int* __restrict__ ep,
                                         const unsigned short* __restrict__ xlb,
                                         int arow, int g, float (&v)[4][8]) {
    int e0 = ep[3 * arow], e1 = ep[3 * arow + 1], e2 = ep[3 * arow + 2];
    const unsigned short* r0 = xlb + (size_t)e0 * D + g * 8;
    const unsigned short* r1 = xlb + (size_t)e1 * D + g * 8;
    const unsigned short* r2 = xlb + (size_t)e2 * D + g * 8;
    #pragma unroll
    for (int ks = 0; ks < 4; ks++) {
        short8v a = *(const short8v*)(r0 + ks * 32);
        short8v b = *(const short8v*)(r1 + ks * 32);
        short8v c = *(const short8v*)(r2 + ks * 32);
        #pragma unroll
        for (int j = 0; j < 8; j++)
            v[ks][j] = bf2f((unsigned short)a[j]) + bf2f((unsigned short)b[j]) +
                       bf2f((unsigned short)c[j]);
    }
}

__device__ __forceinline__ void gatherCSRb(const int* __restrict__ offs,
                                           const int* __restrict__ counts,
                                           const int* __restrict__ csr,
                                           const unsigned short* __restrict__ xcb,
                                           int arow, int g, float (&v)[4][8]) {
    #pragma unroll
    for (int ks = 0; ks < 4; ks++)
        #pragma unroll
        for (int j = 0; j < 8; j++) v[ks][j] = 0.f;
    const int s = offs[arow], e = s + counts[arow];
    for (int p = s; p < e; p++) {
        const unsigned short* q = xcb + (size_t)csr[p] * D + g * 8;
        #pragma unroll
        for (int ks = 0; ks < 4; ks++) {
            short8v a = *(const short8v*)(q + ks * 32);
            #pragma unroll
            for (int j = 0; j < 8; j++) v[ks][j] += bf2f((unsigned short)a[j]);
        }
    }
}

// ---------------- LC: 512 blocks x 512 thr; 128 rows/block; wave=16 rows -----
__global__ __launch_bounds__(512, 4) void lc_mfma(
    const int* __restrict__ edge_lit, const unsigned short* __restrict__ xl_bf,
    unsigned short* xc_bf, float* norms,          // read t-1, write t (same rows)
    const unsigned short* __restrict__ pk,
    const float* __restrict__ bih, const float* __restrict__ bhh,
    float* __restrict__ xc_norm) {
    extern __shared__ __align__(16) unsigned short lds[];  // [0,PKM)=ih, [PKM,2PKM)=hh
    const int tid = threadIdx.x, wid = tid >> 6, lane = tid & 63;
    const int m = lane & 15, g = lane >> 4;
    const int p = blockIdx.x;
    const int blk = (p & 7) * 64 + (p >> 3);    // XCD-chunked, grid=512 bijective
    const int rowbase = blk * 128;
    const int arow = rowbase + wid * 16 + m;

    // stage ih_lc + hh_lc (64 KB contiguous in pk)
    {
        const short8v* src = (const short8v*)pk;
        short8v* dst = (short8v*)lds;
        #pragma unroll
        for (int i = 0; i < 8; i++) dst[i * 512 + tid] = src[i * 512 + tid];
    }
    float v[4][8];
    gather3b(edge_lit, xl_bf, arow, g, v);
    // hidden: bf16 pre-norm row x (1/||row||); scale uniform per lane
    short8v hvb[4];
    {
        const unsigned short* hr = xc_bf + (size_t)arow * D + g * 8;
        #pragma unroll
        for (int ks = 0; ks < 4; ks++) hvb[ks] = *(const short8v*)(hr + ks * 32);
    }
    const float rnh = __builtin_amdgcn_rcpf(norms[arow]);
    __syncthreads();

    short8v ah[4], al[4];
    #pragma unroll
    for (int ks = 0; ks < 4; ks++) cvt_frag(v[ks], ah[ks], al[ks]);

    f32x4 acc[8];
    #pragma unroll
    for (int n = 0; n < 8; n++) acc[n] = (f32x4)0.f;

    #pragma unroll
    for (int ks = 0; ks < 4; ks++)
        #pragma unroll
        for (int n = 0; n < 8; n++)
            mm2(acc[n], ah[ks], al[ks], lds, ((n * 4 + ks) * 64 + lane) * 8);

    float vh[4][8];
    #pragma unroll
    for (int ks = 0; ks < 4; ks++)
        #pragma unroll
        for (int j = 0; j < 8; j++)
            vh[ks][j] = bf2f((unsigned short)hvb[ks][j]) * rnh;
    #pragma unroll
    for (int ks = 0; ks < 4; ks++) cvt_frag(vh[ks], ah[ks], al[ks]);
    #pragma unroll
    for (int ks = 0; ks < 4; ks++)
        #pragma unroll
        for (int n = 0; n < 8; n++)
            mm2(acc[n], ah[ks], al[ks], lds + PKM, ((n * 4 + ks) * 64 + lane) * 8);

    float bias[8];
    #pragma unroll
    for (int n = 0; n < 8; n++) bias[n] = bih[n * 16 + m] + bhh[n * 16 + m];

    const int obase = rowbase + wid * 16 + g * 4;
    #pragma unroll
    for (int r = 0; r < 4; r++) {
        float w[8], ss = 0.f;
        #pragma unroll
        for (int n = 0; n < 8; n++) { w[n] = ftanh(acc[n][r] + bias[n]); ss += w[n] * w[n]; }
        ss += __shfl_xor(ss, 1); ss += __shfl_xor(ss, 2);
        ss += __shfl_xor(ss, 4); ss += __shfl_xor(ss, 8);
        const float rn = __builtin_amdgcn_rsqf(ss);
        const size_t rowoff = (size_t)(obase + r) * D + m;
        #pragma unroll
        for (int n = 0; n < 8; n++) {
            ntst(xc_norm + rowoff + n * 16, w[n] * rn); // write-only f32 -> nt
            xc_bf[rowoff + n * 16] = f2bf(w[n]);        // re-read bf16 -> cached
        }
        if (m == 0) norms[obase + r] = ss * rn;         // ||row|| for next iter
    }
}

// ------- CL: 512 blocks x 512 thr; 64 rows/block; wave=16 rows x N-half ------
__global__ __launch_bounds__(512, 4) void cl_mfma(
    const int* __restrict__ offs, const int* __restrict__ counts,
    const int* __restrict__ csr, const int* __restrict__ perm,
    const unsigned short* __restrict__ xc_bf,
    const unsigned short* __restrict__ xl_src,    // bf16 normalized state (read)
    const unsigned short* __restrict__ pk,
    const float* __restrict__ bih, const float* __restrict__ bhh,
    const float* __restrict__ tv, const float* __restrict__ vw,
    const float* __restrict__ vb,
    unsigned short* __restrict__ xl_dst,          // bf16 normalized state (write)
    float* __restrict__ xl_out,                   // f32 output (t==T only, else null)
    float* __restrict__ truth, float* __restrict__ truth2, float* __restrict__ vote) {
    extern __shared__ __align__(16) unsigned short lds[];
    // buf0 [0,PKM): ih_msg -> later ih_flip ; buf1 [PKM,2PKM): hh
    float* scr = (float*)(lds + 2 * PKM);
    float* ssx = scr; float* twx = scr + 128; float* vwx = scr + 256;

    const int tid = threadIdx.x, wid = tid >> 6, lane = tid & 63;
    const int m = lane & 15, g = lane >> 4;
    const int rw = wid >> 1, nh = wid & 1, nbase = nh * 4;
    const int p0 = blockIdx.x;
    const int blk = (p0 & 7) * 64 + (p0 >> 3);
    const int lbase = blk * 64;
    const int arow = lbase + perm[lbase + rw * 16 + m];

    // stage buf0=ih_msg (mat3), buf1=hh (mat2)
    {
        const short8v* srcA = (const short8v*)(pk + 3 * PKM);
        const short8v* srcB = (const short8v*)(pk + 2 * PKM);
        short8v* d0 = (short8v*)lds;
        short8v* d1 = (short8v*)(lds + PKM);
        #pragma unroll
        for (int i = 0; i < 4; i++) d0[i * 512 + tid] = srcA[i * 512 + tid];
        #pragma unroll
        for (int i = 0; i < 4; i++) d1[i * 512 + tid] = srcB[i * 512 + tid];
    }
    float v[4][8];
    gatherCSRb(offs, counts, csr, xc_bf, arow, g, v);
    // hidden + flip bf16 frags (exact A; issue early, land under msg MFMAs)
    short8v hv[4], fv[4];
    {
        const unsigned short* hr = xl_src + (size_t)arow * D + g * 8;
        const unsigned short* fp = xl_src + (size_t)(arow ^ 256) * D + g * 8;
        #pragma unroll
        for (int ks = 0; ks < 4; ks++) { hv[ks] = *(const short8v*)(hr + ks * 32);
                                         fv[ks] = *(const short8v*)(fp + ks * 32); }
    }
    __syncthreads();                                   // b1

    short8v ah[4], al[4];
    #pragma unroll
    for (int ks = 0; ks < 4; ks++) cvt_frag(v[ks], ah[ks], al[ks]);

    f32x4 acc[4];
    #pragma unroll
    for (int n = 0; n < 4; n++) acc[n] = (f32x4)0.f;

    // T14: prefetch flip-W to regs before msg MFMAs
    short8v fr[4];
    {
        const short8v* srcF = (const short8v*)(pk + 4 * PKM);  // ih_flip
        #pragma unroll
        for (int i = 0; i < 4; i++) fr[i] = srcF[i * 512 + tid];
    }

    #pragma unroll
    for (int ks = 0; ks < 4; ks++)
        #pragma unroll
        for (int nn = 0; nn < 4; nn++)
            mm2(acc[nn], ah[ks], al[ks], lds, (((nbase + nn) * 4 + ks) * 64 + lane) * 8);

    __syncthreads();                                   // b2: msg reads of buf0 done
    {
        short8v* d0 = (short8v*)lds;
        #pragma unroll
        for (int i = 0; i < 4; i++) d0[i * 512 + tid] = fr[i];
    }
    #pragma unroll
    for (int ks = 0; ks < 4; ks++)
        #pragma unroll
        for (int nn = 0; nn < 4; nn++)
            mm1(acc[nn], hv[ks], lds + PKM, (((nbase + nn) * 4 + ks) * 64 + lane) * 8);

    __syncthreads();                                   // b3: flip staged & visible
    #pragma unroll
    for (int ks = 0; ks < 4; ks++)
        #pragma unroll
        for (int nn = 0; nn < 4; nn++)
            mm1(acc[nn], fv[ks], lds, (((nbase + nn) * 4 + ks) * 64 + lane) * 8);

    float bias[4], tvv[4], vwv[4];
    #pragma unroll
    for (int nn = 0; nn < 4; nn++) {
        int n = nbase + nn;
        bias[nn] = bih[n * 16 + m] + bhh[n * 16 + m];
        tvv[nn] = tv[n * 16 + m];
        vwv[nn] = vote ? vw[n * 16 + m] : 0.f;
    }
    float wv[4][4];
    #pragma unroll
    for (int r = 0; r < 4; r++) {
        float ssp = 0.f, twp = 0.f, vwp = 0.f;
        #pragma unroll
        for (int nn = 0; nn < 4; nn++) {
            float w = ftanh(acc[nn][r] + bias[nn]);
            wv[r][nn] = w;
            ssp += w * w; twp += w * tvv[nn]; vwp += w * vwv[nn];
        }
        ssp += __shfl_xor(ssp, 1); ssp += __shfl_xor(ssp, 2);
        ssp += __shfl_xor(ssp, 4); ssp += __shfl_xor(ssp, 8);
        twp += __shfl_xor(twp, 1); twp += __shfl_xor(twp, 2);
        twp += __shfl_xor(twp, 4); twp += __shfl_xor(twp, 8);
        if (vote) {
            vwp += __shfl_xor(vwp, 1); vwp += __shfl_xor(vwp, 2);
            vwp += __shfl_xor(vwp, 4); vwp += __shfl_xor(vwp, 8);
        }
        if (m == 0) {
            int rl = rw * 16 + g * 4 + r;
            ssx[rl * 2 + nh] = ssp;
            twx[rl * 2 + nh] = twp;
            if (vote) vwx[rl * 2 + nh] = vwp;
        }
    }
    __syncthreads();                                   // b4
    const float vb0 = vote ? vb[0] : 0.f;
    #pragma unroll
    for (int r = 0; r < 4; r++) {
        const int rl = rw * 16 + g * 4 + r;
        const int grow = lbase + perm[lbase + rl];
        const float ss = ssx[rl * 2] + ssx[rl * 2 + 1];
        const float rn = __builtin_amdgcn_rsqf(ss);
        const size_t rowoff = (size_t)grow * D + m;
        #pragma unroll
        for (int nn = 0; nn < 4; nn++) {
            const float y = wv[r][nn] * rn;
            xl_dst[rowoff + (nbase + nn) * 16] = f2bf(y);           // re-read -> cached
            if (xl_out) ntst(xl_out + rowoff + (nbase + nn) * 16, y); // write-only -> nt
        }
        if (m == 0 && nh == 0) {
            const float td = rn * (twx[rl * 2] + twx[rl * 2 + 1]);
            ntst(truth + grow, td);
            if (truth2) ntst(truth2 + grow, td);
            if (vote) ntst(vote + grow, rn * (vwx[rl * 2] + vwx[rl * 2 + 1]) + vb0);
        }
    }
}

// ---------------- mean-pool --------------------------------------------------
__global__ void pool_kernel(const float* __restrict__ votes, float* __restrict__ pool) {
    __shared__ float s[4];
    int g = blockIdx.x, t = threadIdx.x;
    float v = votes[g * LITS_PER + t] + votes[g * LITS_PER + 256 + t];
    #pragma unroll
    for (int m = 32; m; m >>= 1) v += __shfl_xor(v, m);
    if ((t & 63) == 0) s[t >> 6] = v;
    __syncthreads();
    if (t == 0) pool[g] = (s[0] + s[1] + s[2] + s[3]) * (1.0f / LITS_PER);
}

// ---------------- launch ----------------------------------------------------
extern "C" void kernel_launch(void* const* d_in, const int* in_sizes, int n_in,
                              void* d_out, int out_size, void* d_ws, size_t ws_size,
                              hipStream_t stream) {
    const int*   edge_lit = (const int*)d_in[1];
    const float* x_l0     = (const float*)d_in[2];
    const float* x_c0     = (const float*)d_in[3];
    const float* W_ih_lc  = (const float*)d_in[4];
    const float* W_hh_lc  = (const float*)d_in[5];
    const float* b_ih_lc  = (const float*)d_in[6];
    const float* b_hh_lc  = (const float*)d_in[7];
    const float* W_ih_cl  = (const float*)d_in[8];
    const float* W_hh_cl  = (const float*)d_in[9];
    const float* b_ih_cl  = (const float*)d_in[10];
    const float* b_hh_cl  = (const float*)d_in[11];
    const float* L_vote_w = (const float*)d_in[12];
    const float* L_vote_b = (const float*)d_in[13];
    const float* true_vec = (const float*)d_in[14];
    // d_in[15] = num_iters (=8, compile-time T)

    float* out   = (float*)d_out;
    float* xl_o  = out + OFF_XL;
    float* call  = out + OFF_CALL;
    float* tall  = out + OFF_TALL;

    // workspace (16B-aligned slices)
    unsigned short* xc_bf  = (unsigned short*)d_ws;          // NC*D bf16
    unsigned short* xl_bf0 = xc_bf + (size_t)NC * D;         // NL*D bf16
    unsigned short* xl_bf1 = xl_bf0 + (size_t)NL * D;        // NL*D bf16
    unsigned short* pk     = xl_bf1 + (size_t)NL * D;        // PK_TOT
    float* norms = (float*)(pk + PK_TOT);                    // NC
    int* counts = (int*)(norms + NC);                        // NL
    int* offs   = counts + NL;                               // NL
    int* cursor = offs + NL;                                 // NL
    int* perm   = cursor + NL;                               // NL
    int* csr    = perm + NL;                                 // (NL/64)*GCAP

    hipMemsetAsync(counts, 0, NL * sizeof(int), stream);

    pack5<<<PK_TOT / 256, 256, 0, stream>>>(W_ih_lc, W_hh_lc, W_hh_cl, W_ih_cl, pk);
    csr_count<<<NE / 256, 256, 0, stream>>>(edge_lit, counts);
    group_scan<<<NL / 64, 64, 0, stream>>>(counts, offs, cursor, perm);
    csr_fill<<<NE / 256, 256, 0, stream>>>(edge_lit, cursor, csr);
    csr_sort<<<NL / 256, 256, 0, stream>>>(offs, counts, csr);

    init_norm<<<(NL + NC) / 4, 256, 0, stream>>>(
        x_l0, x_c0, xl_o, xl_bf0, call, xc_bf, norms,
        true_vec, tall, out + OFF_T0);

    for (int t = 1; t <= T; t++) {
        const unsigned short* src = (t & 1) ? xl_bf0 : xl_bf1;
        unsigned short*       dst = (t & 1) ? xl_bf1 : xl_bf0;
        lc_mfma<<<NC / 128, 512, SHM_LC, stream>>>(
            edge_lit, src, xc_bf, norms, pk, b_ih_lc, b_hh_lc,
            call + (size_t)t * NC * D);
        cl_mfma<<<NL / 64, 512, SHM_CL, stream>>>(
            offs, counts, csr, perm, xc_bf, src, pk,
            b_ih_cl, b_hh_cl, true_vec, L_vote_w, L_vote_b,
            dst, (t == T) ? xl_o : nullptr, tall + (size_t)t * NL,
            (t == T) ? out + OFF_TLAST : nullptr,
            (t == T) ? out + OFF_VOTE : nullptr);
    }

    pool_kernel<<<Bg, 256, 0, stream>>>(out + OFF_VOTE, out + OFF_POOL);
}

// Round 14
// 470.639 us; speedup vs baseline: 1.8089x; 1.0089x over previous
//
#include <hip/hip_runtime.h>
#include <math.h>

// NeuroSAT RNN forward on MI355X — round-13 + 2-way p-unrolled CSR gather in cl
// (double memory-level parallelism on the dependent gather chain).
namespace {
constexpr int NVARS    = 256;
constexpr int LITS_PER = 2 * NVARS;     // 512
constexpr int Bg       = 64;            // graphs
constexpr int NL       = Bg * LITS_PER; // 32768 literals
constexpr int CLS_PER  = 1024;
constexpr int NC       = Bg * CLS_PER;  // 65536 clauses
constexpr int NE       = NC * 3;        // 196608 edges (K=3)
constexpr int D        = 128;
constexpr int T        = 8;             // num_iters (fixed scalar input)
constexpr int GCAP     = 1024;          // csr capacity per 64-literal group

// d_out flat layout (reference tuple order)
constexpr size_t OFF_VOTE  = 0;                                  // [NL]
constexpr size_t OFF_XL    = (size_t)NL;                         // [NL*D]   (x_l state)
constexpr size_t OFF_POOL  = OFF_XL + (size_t)NL * D;            // [Bg]
constexpr size_t OFF_TLAST = OFF_POOL + Bg;                      // [NL]
constexpr size_t OFF_TALL  = OFF_TLAST + NL;                     // [(T+1)*NL]
constexpr size_t OFF_CALL  = OFF_TALL + (size_t)(T + 1) * NL;    // [(T+1)*NC*D] (x_c state)
constexpr size_t OFF_T0    = OFF_CALL + (size_t)(T + 1) * NC * D;// [NL]

// packed weights, single bf16 plane per matrix, frag order [n][ks][lane][8]:
// 0: W_ih_lc | 1: W_hh_lc | 2: W_hh_cl | 3: W_ih_cl[:, :128] | 4: W_ih_cl[:, 128:]
constexpr int PKM    = 16384;           // ushorts per matrix
constexpr int PK_TOT = 5 * PKM;         // 81920
constexpr size_t SHM_LC = 2 * PKM * sizeof(unsigned short);          // 64 KB
constexpr size_t SHM_CL = 2 * PKM * sizeof(unsigned short) + 1536;   // 64 KB + scratch
} // namespace

typedef __attribute__((ext_vector_type(8))) short short8v;
typedef __attribute__((ext_vector_type(4))) float f32x4;

__device__ __forceinline__ unsigned short f2bf(float v) {
    unsigned u = __float_as_uint(v);
    return (unsigned short)((u + 0x7fffu + ((u >> 16) & 1u)) >> 16);  // RNE
}
__device__ __forceinline__ float bf2f(unsigned short b) {
    return __uint_as_float(((unsigned)b) << 16);
}
__device__ __forceinline__ void cvt_frag(const float (&v)[8], short8v& ah, short8v& al) {
    #pragma unroll
    for (int j = 0; j < 8; j++) {
        unsigned short h = f2bf(v[j]);
        ah[j] = (short)h;
        al[j] = (short)f2bf(v[j] - bf2f(h));
    }
}
__device__ __forceinline__ float ftanh(float x) {
    float e = __builtin_amdgcn_exp2f(x * 2.885390081777926814f);
    return 1.0f - 2.0f * __builtin_amdgcn_rcpf(e + 1.0f);
}
// bf16x2: A split (ah+al), B single bf16 plane from LDS. 2 MFMAs, 1 LDS read.
__device__ __forceinline__ void mm2(f32x4& c, short8v ah, short8v al,
                                    const unsigned short* buf, int off) {
    short8v b = *(const short8v*)(buf + off);
    c = __builtin_amdgcn_mfma_f32_16x16x32_bf16(ah, b, c, 0, 0, 0);
    c = __builtin_amdgcn_mfma_f32_16x16x32_bf16(al, b, c, 0, 0, 0);
}
// pure-bf16 A (exact): 1 MFMA
__device__ __forceinline__ void mm1(f32x4& c, short8v a,
                                    const unsigned short* buf, int off) {
    short8v b = *(const short8v*)(buf + off);
    c = __builtin_amdgcn_mfma_f32_16x16x32_bf16(a, b, c, 0, 0, 0);
}
// nontemporal store: evict-first hint for write-only output streams
__device__ __forceinline__ void ntst(float* p, float v) { __builtin_nontemporal_store(v, p); }

// ---------------- W packing (single plane) -----------------------------------
__global__ __launch_bounds__(256) void pack5(
    const float* __restrict__ ihlc, const float* __restrict__ hhlc,
    const float* __restrict__ hhcl, const float* __restrict__ ihcl,
    unsigned short* __restrict__ pk) {
    int idx = blockIdx.x * 256 + threadIdx.x;
    int mat = idx >> 14, rel = idx & 16383;
    int j = rel & 7, lane = (rel >> 3) & 63, ks = (rel >> 9) & 3, n = rel >> 11;
    int r = n * 16 + (lane & 15);
    int k = ks * 32 + (lane >> 4) * 8 + j;
    float w;
    if (mat == 0)      w = ihlc[r * 128 + k];
    else if (mat == 1) w = hhlc[r * 128 + k];
    else if (mat == 2) w = hhcl[r * 128 + k];
    else if (mat == 3) w = ihcl[r * 256 + k];
    else               w = ihcl[r * 256 + 128 + k];
    pk[mat * PKM + rel] = f2bf(w);
}

// ---------------- CSR build (group-strided, fully parallel) -------------------
__global__ void csr_count(const int* __restrict__ edge_lit, int* __restrict__ counts) {
    int e = blockIdx.x * blockDim.x + threadIdx.x;
    if (e < NE) atomicAdd(&counts[edge_lit[e]], 1);
}

// one 64-lane wave per 64-literal group: exclusive scan (offs/cursor) + degree-sort perm
__global__ __launch_bounds__(64) void group_scan(const int* __restrict__ counts,
                                                 int* __restrict__ offs,
                                                 int* __restrict__ cursor,
                                                 int* __restrict__ perm) {
    const int grp = blockIdx.x, i = threadIdx.x;
    const int l = grp * 64 + i;
    const int cnt = counts[l];
    int v = cnt;
    #pragma unroll
    for (int d = 1; d < 64; d <<= 1) {
        int up = __shfl_up(v, d);
        if (i >= d) v += up;
    }
    const int o = grp * GCAP + (v - cnt);
    offs[l] = o;
    cursor[l] = o;
    int rank = 0;
    #pragma unroll 8
    for (int j = 0; j < 64; j++) {
        int dj = __shfl(cnt, j);
        rank += (dj < cnt) || (dj == cnt && j < i);
    }
    perm[grp * 64 + rank] = i;
}

__global__ void csr_fill(const int* __restrict__ edge_lit, int* __restrict__ cursor,
                         int* __restrict__ csr) {
    int e = blockIdx.x * blockDim.x + threadIdx.x;
    if (e < NE) {
        int l = edge_lit[e];
        int p = atomicAdd(&cursor[l], 1);
        csr[p] = e / 3;
    }
}

__global__ void csr_sort(const int* __restrict__ offs, const int* __restrict__ counts,
                         int* __restrict__ csr) {
    int l = blockIdx.x * blockDim.x + threadIdx.x;
    if (l >= NL) return;
    int s = offs[l], e = s + counts[l];
    for (int i = s + 1; i < e; i++) {
        int v = csr[i];
        int j = i - 1;
        while (j >= s && csr[j] > v) { csr[j + 1] = csr[j]; j--; }
        csr[j + 1] = v;
    }
}

// -------- init (both states, one launch): L2-normalize + bf16 shadows --------
__global__ void init_norm(const float* __restrict__ x_l0, const float* __restrict__ x_c0,
                          float* __restrict__ xl_f32, unsigned short* __restrict__ xl_bf,
                          float* __restrict__ xc_f32, unsigned short* __restrict__ xc_bf,
                          float* __restrict__ norms,
                          const float* __restrict__ tv, float* __restrict__ tall,
                          float* __restrict__ t0) {
    int wave = (int)((blockIdx.x * blockDim.x + threadIdx.x) >> 6);
    int lane = threadIdx.x & 63;
    if (wave < NL) {
        const float* r = x_l0 + (size_t)wave * D;
        float v0 = r[lane], v1 = r[lane + 64];
        float ss = v0 * v0 + v1 * v1;
        #pragma unroll
        for (int m = 32; m; m >>= 1) ss += __shfl_xor(ss, m);
        float rn = 1.0f / sqrtf(ss);
        float y0 = v0 * rn, y1 = v1 * rn;
        ntst(xl_f32 + (size_t)wave * D + lane, y0);
        ntst(xl_f32 + (size_t)wave * D + lane + 64, y1);
        unsigned short* ob = xl_bf + (size_t)wave * D;
        ob[lane] = f2bf(y0);
        ob[lane + 64] = f2bf(y1);
        float dv = y0 * tv[lane] + y1 * tv[lane + 64];
        #pragma unroll
        for (int m = 32; m; m >>= 1) dv += __shfl_xor(dv, m);
        if (lane == 0) { ntst(tall + wave, dv); ntst(t0 + wave, dv); }
    } else if (wave < NL + NC) {
        const int row = wave - NL;
        const float* r = x_c0 + (size_t)row * D;
        float v0 = r[lane], v1 = r[lane + 64];
        float ss = v0 * v0 + v1 * v1;
        #pragma unroll
        for (int m = 32; m; m >>= 1) ss += __shfl_xor(ss, m);
        float rn = 1.0f / sqrtf(ss);
        ntst(xc_f32 + (size_t)row * D + lane, v0 * rn);
        ntst(xc_f32 + (size_t)row * D + lane + 64, v1 * rn);
        unsigned short* ob = xc_bf + (size_t)row * D;
        ob[lane] = f2bf(v0);                       // raw bf16 (pre-norm shadow)
        ob[lane + 64] = f2bf(v1);
        if (lane == 0) norms[row] = ss * rn;       // ||row||
    }
}

// -------- gather helpers (bf16 sources) --------------------------------------
__device__ __forceinline__ void gather3b(const int* __restrict__ ep,
                                         const unsigned short* __restrict__ xlb,
                                         int arow, int g, float (&v)[4][8]) {
    int e0 = ep[3 * arow], e1 = ep[3 * arow + 1], e2 = ep[3 * arow + 2];
    const unsigned short* r0 = xlb + (size_t)e0 * D + g * 8;
    const unsigned short* r1 = xlb + (size_t)e1 * D + g * 8;
    const unsigned short* r2 = xlb + (size_t)e2 * D + g * 8;
    #pragma unroll
    for (int ks = 0; ks < 4; ks++) {
        short8v a = *(const short8v*)(r0 + ks * 32);
        short8v b = *(const short8v*)(r1 + ks * 32);
        short8v c = *(const short8v*)(r2 + ks * 32);
        #pragma unroll
        for (int j = 0; j < 8; j++)
            v[ks][j] = bf2f((unsigned short)a[j]) + bf2f((unsigned short)b[j]) +
                       bf2f((unsigned short)c[j]);
    }
}

// 2-way p-unrolled CSR gather: 8 row-loads in flight per trip; sequential
// accumulation order preserved (q0 then q1, p ascending).
__device__ __forceinline__ void gatherCSRb2(const int* __restrict__ offs,
                                            const int* __restrict__ counts,
                                            const int* __restrict__ csr,
                                            const unsigned short* __restrict__ xcb,
                                            int arow, int g, float (&v)[4][8]) {
    #pragma unroll
    for (int ks = 0; ks < 4; ks++)
        #pragma unroll
        for (int j = 0; j < 8; j++) v[ks][j] = 0.f;
    const int s = offs[arow], e = s + counts[arow];
    int p = s;
    for (; p + 1 < e; p += 2) {
        const unsigned short* q0 = xcb + (size_t)csr[p] * D + g * 8;
        const unsigned short* q1 = xcb + (size_t)csr[p + 1] * D + g * 8;
        short8v a0[4], a1[4];
        #pragma unroll
        for (int ks = 0; ks < 4; ks++) a0[ks] = *(const short8v*)(q0 + ks * 32);
        #pragma unroll
        for (int ks = 0; ks < 4; ks++) a1[ks] = *(const short8v*)(q1 + ks * 32);
        #pragma unroll
        for (int ks = 0; ks < 4; ks++)
            #pragma unroll
            for (int j = 0; j < 8; j++) v[ks][j] += bf2f((unsigned short)a0[ks][j]);
        #pragma unroll
        for (int ks = 0; ks < 4; ks++)
            #pragma unroll
            for (int j = 0; j < 8; j++) v[ks][j] += bf2f((unsigned short)a1[ks][j]);
    }
    if (p < e) {
        const unsigned short* q0 = xcb + (size_t)csr[p] * D + g * 8;
        #pragma unroll
        for (int ks = 0; ks < 4; ks++) {
            short8v a = *(const short8v*)(q0 + ks * 32);
            #pragma unroll
            for (int j = 0; j < 8; j++) v[ks][j] += bf2f((unsigned short)a[j]);
        }
    }
}

// ---------------- LC: 512 blocks x 512 thr; 128 rows/block; wave=16 rows -----
__global__ __launch_bounds__(512, 4) void lc_mfma(
    const int* __restrict__ edge_lit, const unsigned short* __restrict__ xl_bf,
    unsigned short* xc_bf, float* norms,          // read t-1, write t (same rows)
    const unsigned short* __restrict__ pk,
    const float* __restrict__ bih, const float* __restrict__ bhh,
    float* __restrict__ xc_norm) {
    extern __shared__ __align__(16) unsigned short lds[];  // [0,PKM)=ih, [PKM,2PKM)=hh
    const int tid = threadIdx.x, wid = tid >> 6, lane = tid & 63;
    const int m = lane & 15, g = lane >> 4;
    const int p = blockIdx.x;
    const int blk = (p & 7) * 64 + (p >> 3);    // XCD-chunked, grid=512 bijective
    const int rowbase = blk * 128;
    const int arow = rowbase + wid * 16 + m;

    // stage ih_lc + hh_lc (64 KB contiguous in pk)
    {
        const short8v* src = (const short8v*)pk;
        short8v* dst = (short8v*)lds;
        #pragma unroll
        for (int i = 0; i < 8; i++) dst[i * 512 + tid] = src[i * 512 + tid];
    }
    float v[4][8];
    gather3b(edge_lit, xl_bf, arow, g, v);
    // hidden: bf16 pre-norm row x (1/||row||); scale uniform per lane
    short8v hvb[4];
    {
        const unsigned short* hr = xc_bf + (size_t)arow * D + g * 8;
        #pragma unroll
        for (int ks = 0; ks < 4; ks++) hvb[ks] = *(const short8v*)(hr + ks * 32);
    }
    const float rnh = __builtin_amdgcn_rcpf(norms[arow]);
    __syncthreads();

    short8v ah[4], al[4];
    #pragma unroll
    for (int ks = 0; ks < 4; ks++) cvt_frag(v[ks], ah[ks], al[ks]);

    f32x4 acc[8];
    #pragma unroll
    for (int n = 0; n < 8; n++) acc[n] = (f32x4)0.f;

    #pragma unroll
    for (int ks = 0; ks < 4; ks++)
        #pragma unroll
        for (int n = 0; n < 8; n++)
            mm2(acc[n], ah[ks], al[ks], lds, ((n * 4 + ks) * 64 + lane) * 8);

    float vh[4][8];
    #pragma unroll
    for (int ks = 0; ks < 4; ks++)
        #pragma unroll
        for (int j = 0; j < 8; j++)
            vh[ks][j] = bf2f((unsigned short)hvb[ks][j]) * rnh;
    #pragma unroll
    for (int ks = 0; ks < 4; ks++) cvt_frag(vh[ks], ah[ks], al[ks]);
    #pragma unroll
    for (int ks = 0; ks < 4; ks++)
        #pragma unroll
        for (int n = 0; n < 8; n++)
            mm2(acc[n], ah[ks], al[ks], lds + PKM, ((n * 4 + ks) * 64 + lane) * 8);

    float bias[8];
    #pragma unroll
    for (int n = 0; n < 8; n++) bias[n] = bih[n * 16 + m] + bhh[n * 16 + m];

    const int obase = rowbase + wid * 16 + g * 4;
    #pragma unroll
    for (int r = 0; r < 4; r++) {
        float w[8], ss = 0.f;
        #pragma unroll
        for (int n = 0; n < 8; n++) { w[n] = ftanh(acc[n][r] + bias[n]); ss += w[n] * w[n]; }
        ss += __shfl_xor(ss, 1); ss += __shfl_xor(ss, 2);
        ss += __shfl_xor(ss, 4); ss += __shfl_xor(ss, 8);
        const float rn = __builtin_amdgcn_rsqf(ss);
        const size_t rowoff = (size_t)(obase + r) * D + m;
        #pragma unroll
        for (int n = 0; n < 8; n++) {
            ntst(xc_norm + rowoff + n * 16, w[n] * rn); // write-only f32 -> nt
            xc_bf[rowoff + n * 16] = f2bf(w[n]);        // re-read bf16 -> cached
        }
        if (m == 0) norms[obase + r] = ss * rn;         // ||row|| for next iter
    }
}

// ------- CL: 512 blocks x 512 thr; 64 rows/block; wave=16 rows x N-half ------
__global__ __launch_bounds__(512, 4) void cl_mfma(
    const int* __restrict__ offs, const int* __restrict__ counts,
    const int* __restrict__ csr, const int* __restrict__ perm,
    const unsigned short* __restrict__ xc_bf,
    const unsigned short* __restrict__ xl_src,    // bf16 normalized state (read)
    const unsigned short* __restrict__ pk,
    const float* __restrict__ bih, const float* __restrict__ bhh,
    const float* __restrict__ tv, const float* __restrict__ vw,
    const float* __restrict__ vb,
    unsigned short* __restrict__ xl_dst,          // bf16 normalized state (write)
    float* __restrict__ xl_out,                   // f32 output (t==T only, else null)
    float* __restrict__ truth, float* __restrict__ truth2, float* __restrict__ vote) {
    extern __shared__ __align__(16) unsigned short lds[];
    // buf0 [0,PKM): ih_msg -> later ih_flip ; buf1 [PKM,2PKM): hh
    float* scr = (float*)(lds + 2 * PKM);
    float* ssx = scr; float* twx = scr + 128; float* vwx = scr + 256;

    const int tid = threadIdx.x, wid = tid >> 6, lane = tid & 63;
    const int m = lane & 15, g = lane >> 4;
    const int rw = wid >> 1, nh = wid & 1, nbase = nh * 4;
    const int p0 = blockIdx.x;
    const int blk = (p0 & 7) * 64 + (p0 >> 3);
    const int lbase = blk * 64;
    const int arow = lbase + perm[lbase + rw * 16 + m];

    // stage buf0=ih_msg (mat3), buf1=hh (mat2)
    {
        const short8v* srcA = (const short8v*)(pk + 3 * PKM);
        const short8v* srcB = (const short8v*)(pk + 2 * PKM);
        short8v* d0 = (short8v*)lds;
        short8v* d1 = (short8v*)(lds + PKM);
        #pragma unroll
        for (int i = 0; i < 4; i++) d0[i * 512 + tid] = srcA[i * 512 + tid];
        #pragma unroll
        for (int i = 0; i < 4; i++) d1[i * 512 + tid] = srcB[i * 512 + tid];
    }
    float v[4][8];
    gatherCSRb2(offs, counts, csr, xc_bf, arow, g, v);
    // hidden + flip bf16 frags (exact A; issue early, land under msg MFMAs)
    short8v hv[4], fv[4];
    {
        const unsigned short* hr = xl_src + (size_t)arow * D + g * 8;
        const unsigned short* fp = xl_src + (size_t)(arow ^ 256) * D + g * 8;
        #pragma unroll
        for (int ks = 0; ks < 4; ks++) { hv[ks] = *(const short8v*)(hr + ks * 32);
                                         fv[ks] = *(const short8v*)(fp + ks * 32); }
    }
    __syncthreads();                                   // b1

    short8v ah[4], al[4];
    #pragma unroll
    for (int ks = 0; ks < 4; ks++) cvt_frag(v[ks], ah[ks], al[ks]);

    f32x4 acc[4];
    #pragma unroll
    for (int n = 0; n < 4; n++) acc[n] = (f32x4)0.f;

    // T14: prefetch flip-W to regs before msg MFMAs
    short8v fr[4];
    {
        const short8v* srcF = (const short8v*)(pk + 4 * PKM);  // ih_flip
        #pragma unroll
        for (int i = 0; i < 4; i++) fr[i] = srcF[i * 512 + tid];
    }

    #pragma unroll
    for (int ks = 0; ks < 4; ks++)
        #pragma unroll
        for (int nn = 0; nn < 4; nn++)
            mm2(acc[nn], ah[ks], al[ks], lds, (((nbase + nn) * 4 + ks) * 64 + lane) * 8);

    __syncthreads();                                   // b2: msg reads of buf0 done
    {
        short8v* d0 = (short8v*)lds;
        #pragma unroll
        for (int i = 0; i < 4; i++) d0[i * 512 + tid] = fr[i];
    }
    #pragma unroll
    for (int ks = 0; ks < 4; ks++)
        #pragma unroll
        for (int nn = 0; nn < 4; nn++)
            mm1(acc[nn], hv[ks], lds + PKM, (((nbase + nn) * 4 + ks) * 64 + lane) * 8);

    __syncthreads();                                   // b3: flip staged & visible
    #pragma unroll
    for (int ks = 0; ks < 4; ks++)
        #pragma unroll
        for (int nn = 0; nn < 4; nn++)
            mm1(acc[nn], fv[ks], lds, (((nbase + nn) * 4 + ks) * 64 + lane) * 8);

    float bias[4], tvv[4], vwv[4];
    #pragma unroll
    for (int nn = 0; nn < 4; nn++) {
        int n = nbase + nn;
        bias[nn] = bih[n * 16 + m] + bhh[n * 16 + m];
        tvv[nn] = tv[n * 16 + m];
        vwv[nn] = vote ? vw[n * 16 + m] : 0.f;
    }
    float wv[4][4];
    #pragma unroll
    for (int r = 0; r < 4; r++) {
        float ssp = 0.f, twp = 0.f, vwp = 0.f;
        #pragma unroll
        for (int nn = 0; nn < 4; nn++) {
            float w = ftanh(acc[nn][r] + bias[nn]);
            wv[r][nn] = w;
            ssp += w * w; twp += w * tvv[nn]; vwp += w * vwv[nn];
        }
        ssp += __shfl_xor(ssp, 1); ssp += __shfl_xor(ssp, 2);
        ssp += __shfl_xor(ssp, 4); ssp += __shfl_xor(ssp, 8);
        twp += __shfl_xor(twp, 1); twp += __shfl_xor(twp, 2);
        twp += __shfl_xor(twp, 4); twp += __shfl_xor(twp, 8);
        if (vote) {
            vwp += __shfl_xor(vwp, 1); vwp += __shfl_xor(vwp, 2);
            vwp += __shfl_xor(vwp, 4); vwp += __shfl_xor(vwp, 8);
        }
        if (m == 0) {
            int rl = rw * 16 + g * 4 + r;
            ssx[rl * 2 + nh] = ssp;
            twx[rl * 2 + nh] = twp;
            if (vote) vwx[rl * 2 + nh] = vwp;
        }
    }
    __syncthreads();                                   // b4
    const float vb0 = vote ? vb[0] : 0.f;
    #pragma unroll
    for (int r = 0; r < 4; r++) {
        const int rl = rw * 16 + g * 4 + r;
        const int grow = lbase + perm[lbase + rl];
        const float ss = ssx[rl * 2] + ssx[rl * 2 + 1];
        const float rn = __builtin_amdgcn_rsqf(ss);
        const size_t rowoff = (size_t)grow * D + m;
        #pragma unroll
        for (int nn = 0; nn < 4; nn++) {
            const float y = wv[r][nn] * rn;
            xl_dst[rowoff + (nbase + nn) * 16] = f2bf(y);           // re-read -> cached
            if (xl_out) ntst(xl_out + rowoff + (nbase + nn) * 16, y); // write-only -> nt
        }
        if (m == 0 && nh == 0) {
            const float td = rn * (twx[rl * 2] + twx[rl * 2 + 1]);
            ntst(truth + grow, td);
            if (truth2) ntst(truth2 + grow, td);
            if (vote) ntst(vote + grow, rn * (vwx[rl * 2] + vwx[rl * 2 + 1]) + vb0);
        }
    }
}

// ---------------- mean-pool --------------------------------------------------
__global__ void pool_kernel(const float* __restrict__ votes, float* __restrict__ pool) {
    __shared__ float s[4];
    int g = blockIdx.x, t = threadIdx.x;
    float v = votes[g * LITS_PER + t] + votes[g * LITS_PER + 256 + t];
    #pragma unroll
    for (int m = 32; m; m >>= 1) v += __shfl_xor(v, m);
    if ((t & 63) == 0) s[t >> 6] = v;
    __syncthreads();
    if (t == 0) pool[g] = (s[0] + s[1] + s[2] + s[3]) * (1.0f / LITS_PER);
}

// ---------------- launch ----------------------------------------------------
extern "C" void kernel_launch(void* const* d_in, const int* in_sizes, int n_in,
                              void* d_out, int out_size, void* d_ws, size_t ws_size,
                              hipStream_t stream) {
    const int*   edge_lit = (const int*)d_in[1];
    const float* x_l0     = (const float*)d_in[2];
    const float* x_c0     = (const float*)d_in[3];
    const float* W_ih_lc  = (const float*)d_in[4];
    const float* W_hh_lc  = (const float*)d_in[5];
    const float* b_ih_lc  = (const float*)d_in[6];
    const float* b_hh_lc  = (const float*)d_in[7];
    const float* W_ih_cl  = (const float*)d_in[8];
    const float* W_hh_cl  = (const float*)d_in[9];
    const float* b_ih_cl  = (const float*)d_in[10];
    const float* b_hh_cl  = (const float*)d_in[11];
    const float* L_vote_w = (const float*)d_in[12];
    const float* L_vote_b = (const float*)d_in[13];
    const float* true_vec = (const float*)d_in[14];
    // d_in[15] = num_iters (=8, compile-time T)

    float* out   = (float*)d_out;
    float* xl_o  = out + OFF_XL;
    float* call  = out + OFF_CALL;
    float* tall  = out + OFF_TALL;

    // workspace (16B-aligned slices)
    unsigned short* xc_bf  = (unsigned short*)d_ws;          // NC*D bf16
    unsigned short* xl_bf0 = xc_bf + (size_t)NC * D;         // NL*D bf16
    unsigned short* xl_bf1 = xl_bf0 + (size_t)NL * D;        // NL*D bf16
    unsigned short* pk     = xl_bf1 + (size_t)NL * D;        // PK_TOT
    float* norms = (float*)(pk + PK_TOT);                    // NC
    int* counts = (int*)(norms + NC);                        // NL
    int* offs   = counts + NL;                               // NL
    int* cursor = offs + NL;                                 // NL
    int* perm   = cursor + NL;                               // NL
    int* csr    = perm + NL;                                 // (NL/64)*GCAP

    hipMemsetAsync(counts, 0, NL * sizeof(int), stream);

    pack5<<<PK_TOT / 256, 256, 0, stream>>>(W_ih_lc, W_hh_lc, W_hh_cl, W_ih_cl, pk);
    csr_count<<<NE / 256, 256, 0, stream>>>(edge_lit, counts);
    group_scan<<<NL / 64, 64, 0, stream>>>(counts, offs, cursor, perm);
    csr_fill<<<NE / 256, 256, 0, stream>>>(edge_lit, cursor, csr);
    csr_sort<<<NL / 256, 256, 0, stream>>>(offs, counts, csr);

    init_norm<<<(NL + NC) / 4, 256, 0, stream>>>(
        x_l0, x_c0, xl_o, xl_bf0, call, xc_bf, norms,
        true_vec, tall, out + OFF_T0);

    for (int t = 1; t <= T; t++) {
        const unsigned short* src = (t & 1) ? xl_bf0 : xl_bf1;
        unsigned short*       dst = (t & 1) ? xl_bf1 : xl_bf0;
        lc_mfma<<<NC / 128, 512, SHM_LC, stream>>>(
            edge_lit, src, xc_bf, norms, pk, b_ih_lc, b_hh_lc,
            call + (size_t)t * NC * D);
        cl_mfma<<<NL / 64, 512, SHM_CL, stream>>>(
            offs, counts, csr, perm, xc_bf, src, pk,
            b_ih_cl, b_hh_cl, true_vec, L_vote_w, L_vote_b,
            dst, (t == T) ? xl_o : nullptr, tall + (size_t)t * NL,
            (t == T) ? out + OFF_TLAST : nullptr,
            (t == T) ? out + OFF_VOTE : nullptr);
    }

    pool_kernel<<<Bg, 256, 0, stream>>>(out + OFF_VOTE, out + OFF_POOL);
}